// Round 3
// baseline (358.252 us; speedup 1.0000x reference)
//
#include <hip/hip_runtime.h>
#include <hip/hip_bf16.h>

#define SCALE 0.125f
#define QSCALE 0.18033688f  // SCALE * log2(e): q pre-scaled -> softmax in log2 domain
#define RESCALE_THR 8.0f    // T13 defer-max threshold (log2 units, P bounded by 2^8)

typedef __attribute__((ext_vector_type(8))) __bf16 bf16x8;
typedef __attribute__((ext_vector_type(4))) float f32x4;
typedef __attribute__((ext_vector_type(4))) short s16x4;
typedef __hip_bfloat16 bf16;

__device__ __forceinline__ void gl_lds16(const bf16* g, bf16* l) {
  __builtin_amdgcn_global_load_lds(
      (const __attribute__((address_space(1))) void*)g,
      (__attribute__((address_space(3))) void*)l, 16, 0, 0);
}

__device__ __forceinline__ float fexp2(float x) {
#if __has_builtin(__builtin_amdgcn_exp2f)
  return __builtin_amdgcn_exp2f(x);
#else
  return exp2f(x);
#endif
}

__device__ __forceinline__ f32x4 zf4() {
  f32x4 v; v[0] = 0.f; v[1] = 0.f; v[2] = 0.f; v[3] = 0.f; return v;
}

// ---------------- fp32 -> bf16 copy (4 elems/thread) ----------------
__global__ __launch_bounds__(256) void conv_bf16_k(const float* __restrict__ in,
                                                   bf16* __restrict__ out, int n4) {
  int i = blockIdx.x * 256 + threadIdx.x;
  if (i >= n4) return;
  const float4 v = reinterpret_cast<const float4*>(in)[i];
  union { bf16 h4[4]; s16x4 s; } u;
  u.h4[0] = __float2bfloat16(v.x);
  u.h4[1] = __float2bfloat16(v.y);
  u.h4[2] = __float2bfloat16(v.z);
  u.h4[3] = __float2bfloat16(v.w);
  reinterpret_cast<s16x4*>(out)[i] = u.s;
}

// ---------------- fp32 [K][N] -> bf16 [N][K] transpose ----------------
__global__ __launch_bounds__(256) void transp_k(const float* __restrict__ W,
                                                bf16* __restrict__ Wt, int K, int N) {
  __shared__ float t[32][33];
  const int tx = threadIdx.x, ty = threadIdx.y;
  const int n0 = blockIdx.x * 32, k0 = blockIdx.y * 32;
#pragma unroll
  for (int i = 0; i < 4; ++i)
    t[ty + 8 * i][tx] = W[(k0 + ty + 8 * i) * N + n0 + tx];
  __syncthreads();
#pragma unroll
  for (int i = 0; i < 4; ++i)
    Wt[(n0 + ty + 8 * i) * K + k0 + tx] = __float2bfloat16(t[tx][ty + 8 * i]);
}

// ---------------- bf16 GEMM, 128x128 tile, BK=32, m97 structure ----------------
struct GemmP {
  const bf16* A;    // [M][1024] row-major
  const bf16* B0;   // Bt [N][1024]
  const bf16* B1;   // gate weights (EPI1) Bt
  const bf16* sT;   // EPI1: s in [B,H,N,D]
  bf16 *q, *k, *vt, *gate, *obf;
  float* out;
  const float* bias;
};

template <int EPI>
__global__ __launch_bounds__(256) void gemm_k(GemmP p) {
  constexpr int K = 1024;
  __shared__ bf16 As[128 * 32];
  __shared__ bf16 Bs[128 * 32];
  const int tid = threadIdx.x;
  const int wid = tid >> 6, lane = tid & 63;
  const int l15 = lane & 15, l4 = lane >> 4;
  const int wr = wid >> 1, wc = wid & 1;
  const int m0 = blockIdx.y * 128, n0 = blockIdx.x * 128;
  const bf16* Arow = p.A + m0 * K;
  const bf16* Brow;
  if (EPI == 1 && n0 >= 3072) Brow = p.B1 + (n0 - 3072) * K;
  else Brow = p.B0 + n0 * K;

  f32x4 acc[4][4];
#pragma unroll
  for (int m = 0; m < 4; ++m)
#pragma unroll
    for (int n = 0; n < 4; ++n) acc[m][n] = zf4();

  const int srow = tid >> 2, skc = tid & 3;
  for (int kt = 0; kt < K; kt += 32) {
#pragma unroll
    for (int it = 0; it < 2; ++it) {
      gl_lds16(Arow + (it * 64 + srow) * K + kt + skc * 8, As + it * 2048 + wid * 512);
      gl_lds16(Brow + (it * 64 + srow) * K + kt + skc * 8, Bs + it * 2048 + wid * 512);
    }
    __syncthreads();
    bf16x8 af[4], bfr[4];
#pragma unroll
    for (int m = 0; m < 4; ++m)
      af[m] = *reinterpret_cast<const bf16x8*>(&As[(wr * 64 + m * 16 + l15) * 32 + 8 * l4]);
#pragma unroll
    for (int n = 0; n < 4; ++n)
      bfr[n] = *reinterpret_cast<const bf16x8*>(&Bs[(wc * 64 + n * 16 + l15) * 32 + 8 * l4]);
#pragma unroll
    for (int m = 0; m < 4; ++m)
#pragma unroll
      for (int n = 0; n < 4; ++n)
        acc[m][n] = __builtin_amdgcn_mfma_f32_16x16x32_bf16(af[m], bfr[n], acc[m][n], 0, 0, 0);
    __syncthreads();
  }

  // epilogue
#pragma unroll
  for (int m = 0; m < 4; ++m) {
    const int gr0 = m0 + wr * 64 + m * 16 + l4 * 4;
    const int bb = gr0 >> 11;
    const int nn0 = gr0 & 2047;
#pragma unroll
    for (int n = 0; n < 4; ++n) {
      const int gc = n0 + wc * 64 + n * 16 + l15;
      if (EPI == 0) {
        const int h = gc >> 6, d = gc & 63;
        bf16* dst = p.obf + ((bb * 16 + h) * 2048 + nn0) * 64 + d;
#pragma unroll
        for (int r = 0; r < 4; ++r) dst[r * 64] = __float2bfloat16(acc[m][n][r]);
      } else if (EPI == 1) {
        if (gc < 3072) {
          const int t = gc >> 10, hd = gc & 1023;
          const int h = hd >> 6, d = hd & 63;
          const int base = ((bb * 16 + h) * 2048 + nn0) * 64 + d;
          if (t == 0) {
            // pre-scale q by SCALE*log2e so flash softmax runs in log2 domain
#pragma unroll
            for (int r = 0; r < 4; ++r)
              p.q[base + r * 64] = __float2bfloat16(acc[m][n][r] * QSCALE);
          } else if (t == 1) {
#pragma unroll
            for (int r = 0; r < 4; ++r)
              p.k[base + r * 64] =
                  __float2bfloat16(acc[m][n][r] + __bfloat162float(p.sT[base + r * 64]));
          } else {
            union { bf16 h4[4]; s16x4 s; } u;
#pragma unroll
            for (int r = 0; r < 4; ++r) u.h4[r] = __float2bfloat16(acc[m][n][r]);
            *reinterpret_cast<s16x4*>(&p.vt[((bb * 16 + h) * 64 + d) * 2048 + nn0]) = u.s;
          }
        } else {
          const int gcc = gc - 3072;
#pragma unroll
          for (int r = 0; r < 4; ++r)
            p.gate[(gr0 + r) * 1024 + gcc] = __float2bfloat16(acc[m][n][r]);
        }
      } else {
        const float bias = p.bias[gc];
#pragma unroll
        for (int r = 0; r < 4; ++r) p.out[(gr0 + r) * 1024 + gc] = acc[m][n][r] + bias;
      }
    }
  }
}

// ---------------- flash attention (1 barrier/tile, K/V double-buffered) ----------------
// qT: [BH][N][D] bf16, pre-scaled by QSCALE. kTb: [BH][N][D] bf16 (k+s).
// vTt: [BH][D][N] bf16. gateb/attng: [B*N][C] bf16.
__global__ __launch_bounds__(256) void flash_k(const bf16* __restrict__ qT,
                                               const bf16* __restrict__ kTb,
                                               const bf16* __restrict__ vTt,
                                               const bf16* __restrict__ gateb,
                                               bf16* __restrict__ attng) {
  __shared__ bf16 Ks[2][64 * 64];    // [key][d], XOR-swizzled 16B chunks, double-buffered
  __shared__ bf16 Vs[2][64 * 64];    // [d][key], XOR-swizzled 16B chunks, double-buffered
  __shared__ bf16 Ps[4][16 * 72];    // per-WAVE P (wave-private: no barrier needed)
  const int tid = threadIdx.x;
  const int wid = tid >> 6, lane = tid & 63;
  const int l15 = lane & 15, l4 = lane >> 4;
  const int qt = blockIdx.x, bh = blockIdx.y;
  const int qr0 = qt * 64 + wid * 16;
  const bf16* qbase = qT + (bh * 2048 + qr0) * 64;
  const bf16x8 qf0 = *reinterpret_cast<const bf16x8*>(&qbase[l15 * 64 + 8 * l4]);
  const bf16x8 qf1 = *reinterpret_cast<const bf16x8*>(&qbase[l15 * 64 + 32 + 8 * l4]);
  const bf16* kbase = kTb + bh * 2048 * 64;
  const bf16* vbase = vTt + bh * 64 * 2048;
  f32x4 o[4];
  float mrun[4], lrun[4];
#pragma unroll
  for (int i = 0; i < 4; ++i) { o[i] = zf4(); mrun[i] = -1e30f; lrun[i] = 0.f; }
  const int srow = tid >> 3, sc = tid & 7;

  // stage tile kt into buffer b (pre-swizzled global source; LDS dest linear)
  auto stage = [&](int b, int kt) {
#pragma unroll
    for (int it = 0; it < 2; ++it) {
      const int row = it * 32 + srow;
      const int c2 = sc ^ (row & 7);
      gl_lds16(kbase + (kt * 64 + row) * 64 + c2 * 8, &Ks[b][it * 2048 + wid * 512]);
      gl_lds16(vbase + row * 2048 + kt * 64 + c2 * 8, &Vs[b][it * 2048 + wid * 512]);
    }
  };

  stage(0, 0);
  __syncthreads();  // implicit vmcnt(0) drain: buf0 ready
  int cur = 0;

  for (int kt = 0; kt < 32; ++kt) {
    if (kt < 31) stage(cur ^ 1, kt + 1);  // prefetch: in flight across whole compute

    // S = Q K^T  (per wave: 16 q-rows x 64 keys), log2 domain (q pre-scaled)
    f32x4 sa[4];
#pragma unroll
    for (int n = 0; n < 4; ++n) sa[n] = zf4();
    __builtin_amdgcn_s_setprio(1);
#pragma unroll
    for (int kk = 0; kk < 2; ++kk) {
      const bf16x8 qv = kk ? qf1 : qf0;
#pragma unroll
      for (int n = 0; n < 4; ++n) {
        const int key = n * 16 + l15;
        const bf16x8 kv = *reinterpret_cast<const bf16x8*>(
            &Ks[cur][key * 64 + ((kk * 4 + l4) ^ (key & 7)) * 8]);
        sa[n] = __builtin_amdgcn_mfma_f32_16x16x32_bf16(qv, kv, sa[n], 0, 0, 0);
      }
    }
    __builtin_amdgcn_s_setprio(0);

    // online softmax; rows (l4*4+r) spread over the 16 lanes sharing l4
    float mt[4];
#pragma unroll
    for (int r = 0; r < 4; ++r)
      mt[r] = fmaxf(fmaxf(sa[0][r], sa[1][r]), fmaxf(sa[2][r], sa[3][r]));
#pragma unroll
    for (int off = 1; off <= 8; off <<= 1) {
#pragma unroll
      for (int r = 0; r < 4; ++r) mt[r] = fmaxf(mt[r], __shfl_xor(mt[r], off, 64));
    }
    // T13 defer-max: skip rescale when max growth bounded (P <= 2^THR, bf16-safe)
    const int ok = (mt[0] <= mrun[0] + RESCALE_THR) & (mt[1] <= mrun[1] + RESCALE_THR) &
                   (mt[2] <= mrun[2] + RESCALE_THR) & (mt[3] <= mrun[3] + RESCALE_THR);
    const bool upd = !__all(ok);
    float fac[4];
    if (upd) {
#pragma unroll
      for (int r = 0; r < 4; ++r) {
        const float mn = fmaxf(mrun[r], mt[r]);
        fac[r] = fexp2(mrun[r] - mn);
        mrun[r] = mn;
      }
    }
    float psum[4] = {0.f, 0.f, 0.f, 0.f};
#pragma unroll
    for (int n = 0; n < 4; ++n) {
#pragma unroll
      for (int r = 0; r < 4; ++r) {
        const float pv = fexp2(sa[n][r] - mrun[r]);
        psum[r] += pv;
        Ps[wid][(l4 * 4 + r) * 72 + n * 16 + l15] = __float2bfloat16(pv);
      }
    }
#pragma unroll
    for (int off = 1; off <= 8; off <<= 1) {
#pragma unroll
      for (int r = 0; r < 4; ++r) psum[r] += __shfl_xor(psum[r], off, 64);
    }
    if (upd) {
#pragma unroll
      for (int r = 0; r < 4; ++r) lrun[r] = lrun[r] * fac[r] + psum[r];
#pragma unroll
      for (int nd = 0; nd < 4; ++nd)
#pragma unroll
        for (int r = 0; r < 4; ++r) o[nd][r] *= fac[r];
    } else {
#pragma unroll
      for (int r = 0; r < 4; ++r) lrun[r] += psum[r];
    }

    // O += P V   (Ps is wave-private; compiler orders write->read via lgkmcnt,
    // per-lane aliasing exists so the ordering cannot be elided)
    __builtin_amdgcn_s_setprio(1);
#pragma unroll
    for (int kk = 0; kk < 2; ++kk) {
      const bf16x8 pa = *reinterpret_cast<const bf16x8*>(&Ps[wid][l15 * 72 + kk * 32 + 8 * l4]);
#pragma unroll
      for (int nd = 0; nd < 4; ++nd) {
        const int d = nd * 16 + l15;
        const bf16x8 vv = *reinterpret_cast<const bf16x8*>(
            &Vs[cur][d * 64 + ((kk * 4 + l4) ^ (d & 7)) * 8]);
        o[nd] = __builtin_amdgcn_mfma_f32_16x16x32_bf16(pa, vv, o[nd], 0, 0, 0);
      }
    }
    __builtin_amdgcn_s_setprio(0);

    __syncthreads();  // drains prefetch (vmcnt(0)) + guards buffer swap
    cur ^= 1;
  }

  const int bb = bh >> 4, h = bh & 15;
  float inv[4];
#pragma unroll
  for (int r = 0; r < 4; ++r) inv[r] = 1.0f / lrun[r];
#pragma unroll
  for (int nd = 0; nd < 4; ++nd) {
    const int col = h * 64 + nd * 16 + l15;
#pragma unroll
    for (int r = 0; r < 4; ++r) {
      const int grow = bb * 2048 + qr0 + l4 * 4 + r;
      const int gi = grow * 1024 + col;
      const float val = o[nd][r] * inv[r] * __bfloat162float(gateb[gi]);
      attng[gi] = __float2bfloat16(val);
    }
  }
}

// ---------------- launcher ----------------
extern "C" void kernel_launch(void* const* d_in, const int* in_sizes, int n_in,
                              void* d_out, int out_size, void* d_ws, size_t ws_size,
                              hipStream_t stream) {
  const float* x = (const float*)d_in[0];
  const float* e = (const float*)d_in[1];
  const float* Wqkv = (const float*)d_in[2];
  const float* Ws = (const float*)d_in[3];
  const float* Wgate = (const float*)d_in[4];
  const float* Wproj = (const float*)d_in[5];
  const float* bproj = (const float*)d_in[6];
  float* out = (float*)d_out;

  char* w = (char*)d_ws;
  auto carve = [&](size_t bytes) -> void* {
    void* p = (void*)w;
    w += (bytes + 255) & ~size_t(255);
    return p;
  };
  // time-disjoint aliases: qT overlays ebf (ebf dead after gemm<0>);
  // attng overlays sT (sT dead after gemm<1>).
  bf16* xbf    = (bf16*)carve(4096UL * 1024 * 2);
  bf16* ebf    = (bf16*)carve(4096UL * 1024 * 2);
  bf16* Wqkvt  = (bf16*)carve(3072UL * 1024 * 2);
  bf16* Wst    = (bf16*)carve(1024UL * 1024 * 2);
  bf16* Wgatet = (bf16*)carve(1024UL * 1024 * 2);
  bf16* Wprojt = (bf16*)carve(1024UL * 1024 * 2);
  bf16* kTb    = (bf16*)carve(32UL * 2048 * 64 * 2);
  bf16* vTt    = (bf16*)carve(32UL * 64 * 2048 * 2);
  bf16* sT     = (bf16*)carve(32UL * 2048 * 64 * 2);
  bf16* gateb  = (bf16*)carve(4096UL * 1024 * 2);
  bf16* qT     = ebf;
  bf16* attng  = sT;

  conv_bf16_k<<<4096, 256, 0, stream>>>(x, xbf, 1048576);
  conv_bf16_k<<<4096, 256, 0, stream>>>(e, ebf, 1048576);
  transp_k<<<dim3(96, 32), dim3(32, 8), 0, stream>>>(Wqkv, Wqkvt, 1024, 3072);
  transp_k<<<dim3(32, 32), dim3(32, 8), 0, stream>>>(Ws, Wst, 1024, 1024);
  transp_k<<<dim3(32, 32), dim3(32, 8), 0, stream>>>(Wgate, Wgatet, 1024, 1024);
  transp_k<<<dim3(32, 32), dim3(32, 8), 0, stream>>>(Wproj, Wprojt, 1024, 1024);

  GemmP ps{};
  ps.A = ebf; ps.B0 = Wst; ps.obf = sT;
  gemm_k<0><<<dim3(8, 32), 256, 0, stream>>>(ps);

  GemmP pq{};
  pq.A = xbf; pq.B0 = Wqkvt; pq.B1 = Wgatet; pq.sT = sT;
  pq.q = qT; pq.k = kTb; pq.vt = vTt; pq.gate = gateb;
  gemm_k<1><<<dim3(32, 32), 256, 0, stream>>>(pq);

  flash_k<<<dim3(32, 32), 256, 0, stream>>>(qT, kTb, vTt, gateb, attng);

  GemmP pp{};
  pp.A = attng; pp.B0 = Wprojt; pp.out = out; pp.bias = bproj;
  gemm_k<2><<<dim3(8, 32), 256, 0, stream>>>(pp);
}

// Round 4
// 302.312 us; speedup vs baseline: 1.1850x; 1.1850x over previous
//
#include <hip/hip_runtime.h>
#include <hip/hip_bf16.h>

#define SCALE 0.125f
#define QSCALE 0.18033688f  // SCALE * log2(e): q pre-scaled -> softmax in log2 domain
#define RESCALE_THR 8.0f    // T13 defer-max threshold (log2 units, P bounded by 2^8)

typedef __attribute__((ext_vector_type(8))) __bf16 bf16x8;
typedef __attribute__((ext_vector_type(4))) float f32x4;
typedef __attribute__((ext_vector_type(4))) short s16x4;
typedef __hip_bfloat16 bf16;

__device__ __forceinline__ void gl_lds16(const bf16* g, bf16* l) {
  __builtin_amdgcn_global_load_lds(
      (const __attribute__((address_space(1))) void*)g,
      (__attribute__((address_space(3))) void*)l, 16, 0, 0);
}

__device__ __forceinline__ float fexp2(float x) {
#if __has_builtin(__builtin_amdgcn_exp2f)
  return __builtin_amdgcn_exp2f(x);
#else
  return exp2f(x);
#endif
}

__device__ __forceinline__ unsigned cvt_pk_bf16(float lo, float hi) {
  unsigned r;
  asm("v_cvt_pk_bf16_f32 %0, %1, %2" : "=v"(r) : "v"(lo), "v"(hi));
  return r;
}

__device__ __forceinline__ f32x4 zf4() {
  f32x4 v; v[0] = 0.f; v[1] = 0.f; v[2] = 0.f; v[3] = 0.f; return v;
}

// ---------------- fp32 -> bf16 copy (4 elems/thread) ----------------
__global__ __launch_bounds__(256) void conv_bf16_k(const float* __restrict__ in,
                                                   bf16* __restrict__ out, int n4) {
  int i = blockIdx.x * 256 + threadIdx.x;
  if (i >= n4) return;
  const float4 v = reinterpret_cast<const float4*>(in)[i];
  union { bf16 h4[4]; s16x4 s; } u;
  u.h4[0] = __float2bfloat16(v.x);
  u.h4[1] = __float2bfloat16(v.y);
  u.h4[2] = __float2bfloat16(v.z);
  u.h4[3] = __float2bfloat16(v.w);
  reinterpret_cast<s16x4*>(out)[i] = u.s;
}

// ---------------- fp32 [K][N] -> bf16 [N][K] transpose ----------------
__global__ __launch_bounds__(256) void transp_k(const float* __restrict__ W,
                                                bf16* __restrict__ Wt, int K, int N) {
  __shared__ float t[32][33];
  const int tx = threadIdx.x, ty = threadIdx.y;
  const int n0 = blockIdx.x * 32, k0 = blockIdx.y * 32;
#pragma unroll
  for (int i = 0; i < 4; ++i)
    t[ty + 8 * i][tx] = W[(k0 + ty + 8 * i) * N + n0 + tx];
  __syncthreads();
#pragma unroll
  for (int i = 0; i < 4; ++i)
    Wt[(n0 + ty + 8 * i) * K + k0 + tx] = __float2bfloat16(t[tx][ty + 8 * i]);
}

// ---------------- bf16 GEMM, 128x128 tile, BK=32, m97 structure ----------------
struct GemmP {
  const bf16* A;    // [M][1024] row-major
  const bf16* B0;   // Bt [N][1024]
  const bf16* B1;   // gate weights (EPI1) Bt
  const bf16* sT;   // EPI1: s in [B,H,N,D]
  bf16 *q, *k, *vt, *gate, *obf;
  float* out;
  const float* bias;
};

template <int EPI>
__global__ __launch_bounds__(256) void gemm_k(GemmP p) {
  constexpr int K = 1024;
  __shared__ bf16 As[128 * 32];
  __shared__ bf16 Bs[128 * 32];
  const int tid = threadIdx.x;
  const int wid = tid >> 6, lane = tid & 63;
  const int l15 = lane & 15, l4 = lane >> 4;
  const int wr = wid >> 1, wc = wid & 1;
  const int m0 = blockIdx.y * 128, n0 = blockIdx.x * 128;
  const bf16* Arow = p.A + m0 * K;
  const bf16* Brow;
  if (EPI == 1 && n0 >= 3072) Brow = p.B1 + (n0 - 3072) * K;
  else Brow = p.B0 + n0 * K;

  f32x4 acc[4][4];
#pragma unroll
  for (int m = 0; m < 4; ++m)
#pragma unroll
    for (int n = 0; n < 4; ++n) acc[m][n] = zf4();

  const int srow = tid >> 2, skc = tid & 3;
  for (int kt = 0; kt < K; kt += 32) {
#pragma unroll
    for (int it = 0; it < 2; ++it) {
      gl_lds16(Arow + (it * 64 + srow) * K + kt + skc * 8, As + it * 2048 + wid * 512);
      gl_lds16(Brow + (it * 64 + srow) * K + kt + skc * 8, Bs + it * 2048 + wid * 512);
    }
    __syncthreads();
    bf16x8 af[4], bfr[4];
#pragma unroll
    for (int m = 0; m < 4; ++m)
      af[m] = *reinterpret_cast<const bf16x8*>(&As[(wr * 64 + m * 16 + l15) * 32 + 8 * l4]);
#pragma unroll
    for (int n = 0; n < 4; ++n)
      bfr[n] = *reinterpret_cast<const bf16x8*>(&Bs[(wc * 64 + n * 16 + l15) * 32 + 8 * l4]);
#pragma unroll
    for (int m = 0; m < 4; ++m)
#pragma unroll
      for (int n = 0; n < 4; ++n)
        acc[m][n] = __builtin_amdgcn_mfma_f32_16x16x32_bf16(af[m], bfr[n], acc[m][n], 0, 0, 0);
    __syncthreads();
  }

  // epilogue
#pragma unroll
  for (int m = 0; m < 4; ++m) {
    const int gr0 = m0 + wr * 64 + m * 16 + l4 * 4;
    const int bb = gr0 >> 11;
    const int nn0 = gr0 & 2047;
#pragma unroll
    for (int n = 0; n < 4; ++n) {
      const int gc = n0 + wc * 64 + n * 16 + l15;
      if (EPI == 1) {
        if (gc < 3072) {
          const int t = gc >> 10, hd = gc & 1023;
          const int h = hd >> 6, d = hd & 63;
          const int base = ((bb * 16 + h) * 2048 + nn0) * 64 + d;
          if (t == 0) {
            // pre-scale q by SCALE*log2e so flash softmax runs in log2 domain
#pragma unroll
            for (int r = 0; r < 4; ++r)
              p.q[base + r * 64] = __float2bfloat16(acc[m][n][r] * QSCALE);
          } else if (t == 1) {
#pragma unroll
            for (int r = 0; r < 4; ++r)
              p.k[base + r * 64] =
                  __float2bfloat16(acc[m][n][r] + __bfloat162float(p.sT[base + r * 64]));
          } else {
            union { bf16 h4[4]; s16x4 s; } u;
#pragma unroll
            for (int r = 0; r < 4; ++r) u.h4[r] = __float2bfloat16(acc[m][n][r]);
            *reinterpret_cast<s16x4*>(&p.vt[((bb * 16 + h) * 64 + d) * 2048 + nn0]) = u.s;
          }
        } else {
          const int gcc = gc - 3072;
#pragma unroll
          for (int r = 0; r < 4; ++r)
            p.gate[(gr0 + r) * 1024 + gcc] = __float2bfloat16(acc[m][n][r]);
        }
      }
    }
  }
}

// ---------------- bf16 GEMM, 64x128 tile (for N=1024 GEMMs: 512 blocks = 2/CU) ----------------
template <int EPI>
__global__ __launch_bounds__(256) void gemm2_k(GemmP p) {
  constexpr int K = 1024;
  __shared__ bf16 As[64 * 32];
  __shared__ bf16 Bs[128 * 32];
  const int tid = threadIdx.x;
  const int wid = tid >> 6, lane = tid & 63;
  const int l15 = lane & 15, l4 = lane >> 4;
  const int wc = wid;  // 4 waves x (64M x 32N)
  const int m0 = blockIdx.y * 64, n0 = blockIdx.x * 128;
  const bf16* Arow = p.A + m0 * K;
  const bf16* Brow = p.B0 + n0 * K;

  f32x4 acc[4][2];
#pragma unroll
  for (int m = 0; m < 4; ++m)
#pragma unroll
    for (int n = 0; n < 2; ++n) acc[m][n] = zf4();

  const int srowA = tid >> 2, skc = tid & 3;  // A: 64 rows x 4 chunks
  for (int kt = 0; kt < K; kt += 32) {
    gl_lds16(Arow + srowA * K + kt + skc * 8, As + wid * 512);
#pragma unroll
    for (int it = 0; it < 2; ++it)
      gl_lds16(Brow + (it * 64 + srowA) * K + kt + skc * 8, Bs + it * 2048 + wid * 512);
    __syncthreads();
    bf16x8 af[4], bfr[2];
#pragma unroll
    for (int m = 0; m < 4; ++m)
      af[m] = *reinterpret_cast<const bf16x8*>(&As[(m * 16 + l15) * 32 + 8 * l4]);
#pragma unroll
    for (int n = 0; n < 2; ++n)
      bfr[n] = *reinterpret_cast<const bf16x8*>(&Bs[(wc * 32 + n * 16 + l15) * 32 + 8 * l4]);
#pragma unroll
    for (int m = 0; m < 4; ++m)
#pragma unroll
      for (int n = 0; n < 2; ++n)
        acc[m][n] = __builtin_amdgcn_mfma_f32_16x16x32_bf16(af[m], bfr[n], acc[m][n], 0, 0, 0);
    __syncthreads();
  }

#pragma unroll
  for (int m = 0; m < 4; ++m) {
    const int gr0 = m0 + m * 16 + l4 * 4;
    const int bb = gr0 >> 11;
    const int nn0 = gr0 & 2047;
#pragma unroll
    for (int n = 0; n < 2; ++n) {
      const int gc = n0 + wc * 32 + n * 16 + l15;
      if (EPI == 0) {
        const int h = gc >> 6, d = gc & 63;
        bf16* dst = p.obf + ((bb * 16 + h) * 2048 + nn0) * 64 + d;
#pragma unroll
        for (int r = 0; r < 4; ++r) dst[r * 64] = __float2bfloat16(acc[m][n][r]);
      } else {
        const float bias = p.bias[gc];
#pragma unroll
        for (int r = 0; r < 4; ++r) p.out[(gr0 + r) * 1024 + gc] = acc[m][n][r] + bias;
      }
    }
  }
}

// ---------------- flash attention (swapped-operand, in-register softmax) ----------------
// qT: [BH][N][D] bf16 pre-scaled by QSCALE. kTb: [BH][N][D] bf16 (k+s).
// vTt: [BH][D][N] bf16. gateb/attng: [B*N][C] bf16.
// Swapped QK: sa[n] = mfma(K,Q) -> lane (l15,l4) holds S[key=n*16+l4*4+r][qrow=l15].
// Row softmax: 15 in-lane fmax + shfl_xor(16,32). P exchanged to PV B-frag layout
// via cvt_pk + ds_bpermute (no LDS P buffer).
__global__ __launch_bounds__(256) void flash_k(const bf16* __restrict__ qT,
                                               const bf16* __restrict__ kTb,
                                               const bf16* __restrict__ vTt,
                                               const bf16* __restrict__ gateb,
                                               bf16* __restrict__ attng) {
  __shared__ bf16 Ks[2][64 * 64];  // [key][d], XOR-swizzled 16B chunks, double-buffered
  __shared__ bf16 Vs[2][64 * 64];  // [d][key], XOR-swizzled 16B chunks, double-buffered
  const int tid = threadIdx.x;
  const int wid = tid >> 6, lane = tid & 63;
  const int l15 = lane & 15, l4 = lane >> 4;
  const int hbit = lane >> 5;  // bit5 of lane
  const int qt = blockIdx.x, bh = blockIdx.y;
  const int qr0 = qt * 64 + wid * 16;
  const bf16* qbase = qT + (bh * 2048 + qr0) * 64;
  const bf16x8 qf0 = *reinterpret_cast<const bf16x8*>(&qbase[l15 * 64 + 8 * l4]);
  const bf16x8 qf1 = *reinterpret_cast<const bf16x8*>(&qbase[l15 * 64 + 32 + 8 * l4]);
  const bf16* kbase = kTb + bh * 2048 * 64;
  const bf16* vbase = vTt + bh * 64 * 2048;
  // bpermute source-lane addrs (bytes): src = (q_t<<5) | (q_s<<4) | l15
  const int srcQ0 = (((lane & 16) << 1) | (lane & 15)) << 2;
  const int srcQ1 = srcQ0 | 64;

  f32x4 o[4];  // O^T frags: o[nd][r] = O^T[d=nd*16+l4*4+r][qrow=l15]
#pragma unroll
  for (int i = 0; i < 4; ++i) o[i] = zf4();
  float mrun = -1e30f, lrun = 0.f;
  const int srow = tid >> 3, sc = tid & 7;

  auto stage = [&](int b, int kt) {
#pragma unroll
    for (int it = 0; it < 2; ++it) {
      const int row = it * 32 + srow;
      const int c2 = sc ^ (row & 7);  // pre-swizzled global source; LDS stays linear
      gl_lds16(kbase + (kt * 64 + row) * 64 + c2 * 8, &Ks[b][it * 2048 + wid * 512]);
      gl_lds16(vbase + row * 2048 + kt * 64 + c2 * 8, &Vs[b][it * 2048 + wid * 512]);
    }
  };

  stage(0, 0);
  __syncthreads();
  int cur = 0;

  for (int kt = 0; kt < 32; ++kt) {
    if (kt < 31) stage(cur ^ 1, kt + 1);  // prefetch in flight across compute

    // S^T = K Q^T (swapped): 16 keys/lane for q-row l15
    f32x4 sa[4];
#pragma unroll
    for (int n = 0; n < 4; ++n) sa[n] = zf4();
    __builtin_amdgcn_s_setprio(1);
#pragma unroll
    for (int kk = 0; kk < 2; ++kk) {
      const bf16x8 qv = kk ? qf1 : qf0;
#pragma unroll
      for (int n = 0; n < 4; ++n) {
        const int key = n * 16 + l15;
        const bf16x8 kv = *reinterpret_cast<const bf16x8*>(
            &Ks[cur][key * 64 + ((kk * 4 + l4) ^ (key & 7)) * 8]);
        sa[n] = __builtin_amdgcn_mfma_f32_16x16x32_bf16(kv, qv, sa[n], 0, 0, 0);
      }
    }
    __builtin_amdgcn_s_setprio(0);

    // row max: in-lane 16 + 2 shfl rounds
    float mt = sa[0][0];
#pragma unroll
    for (int n = 0; n < 4; ++n)
#pragma unroll
      for (int r = 0; r < 4; ++r) mt = fmaxf(mt, sa[n][r]);
    mt = fmaxf(mt, __shfl_xor(mt, 16, 64));
    mt = fmaxf(mt, __shfl_xor(mt, 32, 64));

    // T13 defer-max
    const bool upd = !__all(mt <= mrun + RESCALE_THR);
    float fac = 1.f;
    if (upd) {
      const float mn = fmaxf(mrun, mt);
      fac = fexp2(mrun - mn);
      mrun = mn;
    }

    float p[4][4];
    float psum = 0.f;
#pragma unroll
    for (int n = 0; n < 4; ++n)
#pragma unroll
      for (int r = 0; r < 4; ++r) {
        p[n][r] = fexp2(sa[n][r] - mrun);
        psum += p[n][r];
      }
    psum += __shfl_xor(psum, 16, 64);
    psum += __shfl_xor(psum, 32, 64);
    if (upd) {
      lrun = lrun * fac + psum;
#pragma unroll
      for (int nd = 0; nd < 4; ++nd)
#pragma unroll
        for (int r = 0; r < 4; ++r) o[nd][r] *= fac;
    } else {
      lrun += psum;
    }

    // pack P to bf16 pairs: Cp[n][0]=keys(r0,r1), Cp[n][1]=keys(r2,r3)
    int Cp[4][2];
#pragma unroll
    for (int n = 0; n < 4; ++n) {
      Cp[n][0] = (int)cvt_pk_bf16(p[n][0], p[n][1]);
      Cp[n][1] = (int)cvt_pk_bf16(p[n][2], p[n][3]);
    }

    // O^T += V^T P^T : pa[j] = P[qrow=l15][key=kk*32+l4*8+j] via bpermute
    __builtin_amdgcn_s_setprio(1);
#pragma unroll
    for (int kk = 0; kk < 2; ++kk) {
      const int x0 = __builtin_amdgcn_ds_bpermute(srcQ0, Cp[2 * kk][0]);
      const int x1 = __builtin_amdgcn_ds_bpermute(srcQ0, Cp[2 * kk + 1][0]);
      const int y0 = __builtin_amdgcn_ds_bpermute(srcQ0, Cp[2 * kk][1]);
      const int y1 = __builtin_amdgcn_ds_bpermute(srcQ0, Cp[2 * kk + 1][1]);
      const int z0 = __builtin_amdgcn_ds_bpermute(srcQ1, Cp[2 * kk][0]);
      const int z1 = __builtin_amdgcn_ds_bpermute(srcQ1, Cp[2 * kk + 1][0]);
      const int t0 = __builtin_amdgcn_ds_bpermute(srcQ1, Cp[2 * kk][1]);
      const int t1 = __builtin_amdgcn_ds_bpermute(srcQ1, Cp[2 * kk + 1][1]);
      union { int u[4]; bf16x8 v; } pw;
      pw.u[0] = hbit ? x1 : x0;
      pw.u[1] = hbit ? y1 : y0;
      pw.u[2] = hbit ? z1 : z0;
      pw.u[3] = hbit ? t1 : t0;
#pragma unroll
      for (int nd = 0; nd < 4; ++nd) {
        const int d = nd * 16 + l15;
        const bf16x8 vv = *reinterpret_cast<const bf16x8*>(
            &Vs[cur][d * 64 + ((kk * 4 + l4) ^ (d & 7)) * 8]);
        o[nd] = __builtin_amdgcn_mfma_f32_16x16x32_bf16(vv, pw.v, o[nd], 0, 0, 0);
      }
    }
    __builtin_amdgcn_s_setprio(0);

    __syncthreads();  // drains prefetch + guards buffer swap
    cur ^= 1;
  }

  // epilogue: lane writes 4 consecutive bf16 per nd at row qrow=l15
  const int bb = bh >> 4, h = bh & 15;
  const int grow = bb * 2048 + qr0 + l15;
  const float inv = 1.0f / lrun;
#pragma unroll
  for (int nd = 0; nd < 4; ++nd) {
    const int gi = grow * 1024 + h * 64 + nd * 16 + l4 * 4;
    union { s16x4 s; bf16 h4[4]; } gu, ou;
    gu.s = *reinterpret_cast<const s16x4*>(&gateb[gi]);
#pragma unroll
    for (int r = 0; r < 4; ++r)
      ou.h4[r] = __float2bfloat16(o[nd][r] * inv * __bfloat162float(gu.h4[r]));
    *reinterpret_cast<s16x4*>(&attng[gi]) = ou.s;
  }
}

// ---------------- launcher ----------------
extern "C" void kernel_launch(void* const* d_in, const int* in_sizes, int n_in,
                              void* d_out, int out_size, void* d_ws, size_t ws_size,
                              hipStream_t stream) {
  const float* x = (const float*)d_in[0];
  const float* e = (const float*)d_in[1];
  const float* Wqkv = (const float*)d_in[2];
  const float* Ws = (const float*)d_in[3];
  const float* Wgate = (const float*)d_in[4];
  const float* Wproj = (const float*)d_in[5];
  const float* bproj = (const float*)d_in[6];
  float* out = (float*)d_out;

  char* w = (char*)d_ws;
  auto carve = [&](size_t bytes) -> void* {
    void* p = (void*)w;
    w += (bytes + 255) & ~size_t(255);
    return p;
  };
  // time-disjoint aliases: qT overlays ebf (ebf dead after gemm<0>);
  // attng overlays sT (sT dead after gemm<1>).
  bf16* xbf    = (bf16*)carve(4096UL * 1024 * 2);
  bf16* ebf    = (bf16*)carve(4096UL * 1024 * 2);
  bf16* Wqkvt  = (bf16*)carve(3072UL * 1024 * 2);
  bf16* Wst    = (bf16*)carve(1024UL * 1024 * 2);
  bf16* Wgatet = (bf16*)carve(1024UL * 1024 * 2);
  bf16* Wprojt = (bf16*)carve(1024UL * 1024 * 2);
  bf16* kTb    = (bf16*)carve(32UL * 2048 * 64 * 2);
  bf16* vTt    = (bf16*)carve(32UL * 64 * 2048 * 2);
  bf16* sT     = (bf16*)carve(32UL * 2048 * 64 * 2);
  bf16* gateb  = (bf16*)carve(4096UL * 1024 * 2);
  bf16* qT     = ebf;
  bf16* attng  = sT;

  conv_bf16_k<<<4096, 256, 0, stream>>>(x, xbf, 1048576);
  conv_bf16_k<<<4096, 256, 0, stream>>>(e, ebf, 1048576);
  transp_k<<<dim3(96, 32), dim3(32, 8), 0, stream>>>(Wqkv, Wqkvt, 1024, 3072);
  transp_k<<<dim3(32, 32), dim3(32, 8), 0, stream>>>(Ws, Wst, 1024, 1024);
  transp_k<<<dim3(32, 32), dim3(32, 8), 0, stream>>>(Wgate, Wgatet, 1024, 1024);
  transp_k<<<dim3(32, 32), dim3(32, 8), 0, stream>>>(Wproj, Wprojt, 1024, 1024);

  GemmP ps{};
  ps.A = ebf; ps.B0 = Wst; ps.obf = sT;
  gemm2_k<0><<<dim3(8, 64), 256, 0, stream>>>(ps);

  GemmP pq{};
  pq.A = xbf; pq.B0 = Wqkvt; pq.B1 = Wgatet; pq.sT = sT;
  pq.q = qT; pq.k = kTb; pq.vt = vTt; pq.gate = gateb;
  gemm_k<1><<<dim3(32, 32), 256, 0, stream>>>(pq);

  flash_k<<<dim3(32, 32), 256, 0, stream>>>(qT, kTb, vTt, gateb, attng);

  GemmP pp{};
  pp.A = attng; pp.B0 = Wprojt; pp.out = out; pp.bias = bproj;
  gemm2_k<2><<<dim3(8, 64), 256, 0, stream>>>(pp);
}

// Round 5
// 279.655 us; speedup vs baseline: 1.2810x; 1.0810x over previous
//
#include <hip/hip_runtime.h>
#include <hip/hip_bf16.h>

#define SCALE 0.125f
#define QSCALE 0.18033688f  // SCALE * log2(e): q pre-scaled -> softmax in log2 domain
#define RESCALE_THR 8.0f    // T13 defer-max threshold (log2 units, P bounded by 2^8)

typedef __attribute__((ext_vector_type(8))) __bf16 bf16x8;
typedef __attribute__((ext_vector_type(4))) float f32x4;
typedef __attribute__((ext_vector_type(4))) short s16x4;
typedef __hip_bfloat16 bf16;

__device__ __forceinline__ void gl_lds16(const bf16* g, bf16* l) {
  __builtin_amdgcn_global_load_lds(
      (const __attribute__((address_space(1))) void*)g,
      (__attribute__((address_space(3))) void*)l, 16, 0, 0);
}

__device__ __forceinline__ float fexp2(float x) {
#if __has_builtin(__builtin_amdgcn_exp2f)
  return __builtin_amdgcn_exp2f(x);
#else
  return exp2f(x);
#endif
}

__device__ __forceinline__ unsigned cvt_pk_bf16(float lo, float hi) {
  unsigned r;
  asm("v_cvt_pk_bf16_f32 %0, %1, %2" : "=v"(r) : "v"(lo), "v"(hi));
  return r;
}

__device__ __forceinline__ f32x4 zf4() {
  f32x4 v; v[0] = 0.f; v[1] = 0.f; v[2] = 0.f; v[3] = 0.f; return v;
}

// ---------------- fp32 -> bf16 copy (4 elems/thread) ----------------
__global__ __launch_bounds__(256) void conv_bf16_k(const float* __restrict__ in,
                                                   bf16* __restrict__ out, int n4) {
  int i = blockIdx.x * 256 + threadIdx.x;
  if (i >= n4) return;
  const float4 v = reinterpret_cast<const float4*>(in)[i];
  union { bf16 h4[4]; s16x4 s; } u;
  u.h4[0] = __float2bfloat16(v.x);
  u.h4[1] = __float2bfloat16(v.y);
  u.h4[2] = __float2bfloat16(v.z);
  u.h4[3] = __float2bfloat16(v.w);
  reinterpret_cast<s16x4*>(out)[i] = u.s;
}

// ---------------- fp32 [K][N] -> bf16 [N][K] transpose ----------------
__global__ __launch_bounds__(256) void transp_k(const float* __restrict__ W,
                                                bf16* __restrict__ Wt, int K, int N) {
  __shared__ float t[32][33];
  const int tx = threadIdx.x, ty = threadIdx.y;
  const int n0 = blockIdx.x * 32, k0 = blockIdx.y * 32;
#pragma unroll
  for (int i = 0; i < 4; ++i)
    t[ty + 8 * i][tx] = W[(k0 + ty + 8 * i) * N + n0 + tx];
  __syncthreads();
#pragma unroll
  for (int i = 0; i < 4; ++i)
    Wt[(n0 + ty + 8 * i) * K + k0 + tx] = __float2bfloat16(t[tx][ty + 8 * i]);
}

struct GemmP {
  const bf16* A;    // [M][1024] row-major
  const bf16* B0;   // Bt [N][1024]
  const bf16* B1;   // gate weights (EPI1) Bt
  const bf16* sT;   // EPI1: s in [B,H,N,D]
  bf16 *q, *k, *vt, *gate, *obf;
  float* out;
  const float* bias;
};

// ---------------- 256x256 4-phase bf16 GEMM (qkv+gate), BK=64, 8 waves ----------------
// Staging of tile t+1 front-loaded into phases 0-1; tile-boundary vmcnt(0) has
// >=2 phases of slack and no younger loads in flight (counted-vmcnt effect).
// LDS reads swizzled chunk ^= (row&7) via pre-swizzled global source (rule #21).
__global__ __launch_bounds__(512, 2) void gemm256_k(GemmP p) {
  constexpr int K = 1024;
  constexpr int NT = 16;  // K / 64
  __shared__ bf16 AB[2][2][256 * 64];  // [buf][A/B][row*64+col]
  const int tid = threadIdx.x;
  const int wid = tid >> 6, lane = tid & 63;
  const int l15 = lane & 15, l4 = lane >> 4;
  const int wr = wid >> 2, wc = wid & 3;  // 2x4 waves, each 128x64 output

  // XCD-bijective swizzle of 256 blocks (256 % 8 == 0)
  const int bid0 = blockIdx.y * 16 + blockIdx.x;
  const int bid = (bid0 & 7) * 32 + (bid0 >> 3);
  const int m0 = (bid >> 4) * 256, n0 = (bid & 15) * 256;

  const bf16* Arow = p.A + (size_t)m0 * K;
  const bf16* Brow = (n0 >= 3072) ? p.B1 + (size_t)(n0 - 3072) * K
                                  : p.B0 + (size_t)n0 * K;

  f32x4 acc[8][4];
#pragma unroll
  for (int m = 0; m < 8; ++m)
#pragma unroll
    for (int n = 0; n < 4; ++n) acc[m][n] = zf4();

  const int srow = tid >> 3, sc = tid & 7;  // 64 rows/sweep, 8x16B chunks/row
  auto stageA = [&](int b, int kt) {
#pragma unroll
    for (int s = 0; s < 4; ++s) {
      const int r = s * 64 + srow;
      const int c2 = sc ^ (r & 7);
      gl_lds16(Arow + (size_t)r * K + kt * 64 + c2 * 8, &AB[b][0][r * 64 + sc * 8]);
    }
  };
  auto stageB = [&](int b, int kt) {
#pragma unroll
    for (int s = 0; s < 4; ++s) {
      const int r = s * 64 + srow;
      const int c2 = sc ^ (r & 7);
      gl_lds16(Brow + (size_t)r * K + kt * 64 + c2 * 8, &AB[b][1][r * 64 + sc * 8]);
    }
  };

  stageA(0, 0);
  stageB(0, 0);
  __syncthreads();  // full drain: buf0 ready
  int cur = 0;

  for (int kt = 0; kt < NT; ++kt) {
    bf16x8 bfv[4][2];
#pragma unroll
    for (int q = 0; q < 4; ++q) {
      // ds-reads for this phase (compiler inserts lgkmcnt before MFMA use)
      bf16x8 af[2][2];
#pragma unroll
      for (int mm = 0; mm < 2; ++mm) {
        const int row = wr * 128 + (q * 2 + mm) * 16 + l15;
#pragma unroll
        for (int ks = 0; ks < 2; ++ks)
          af[mm][ks] = *reinterpret_cast<const bf16x8*>(
              &AB[cur][0][row * 64 + ((ks * 4 + l4) ^ (row & 7)) * 8]);
      }
      if (q == 0) {
#pragma unroll
        for (int n = 0; n < 4; ++n) {
          const int row = wc * 64 + n * 16 + l15;
#pragma unroll
          for (int ks = 0; ks < 2; ++ks)
            bfv[n][ks] = *reinterpret_cast<const bf16x8*>(
                &AB[cur][1][row * 64 + ((ks * 4 + l4) ^ (row & 7)) * 8]);
        }
      }
      // front-loaded staging of next tile (phases 0-1 only)
      if (q == 0 && kt + 1 < NT) stageA(cur ^ 1, kt + 1);
      if (q == 1 && kt + 1 < NT) stageB(cur ^ 1, kt + 1);

      __builtin_amdgcn_s_barrier();
      __builtin_amdgcn_s_setprio(1);
#pragma unroll
      for (int mm = 0; mm < 2; ++mm)
#pragma unroll
        for (int n = 0; n < 4; ++n)
#pragma unroll
          for (int ks = 0; ks < 2; ++ks)
            acc[q * 2 + mm][n] = __builtin_amdgcn_mfma_f32_16x16x32_bf16(
                af[mm][ks], bfv[n][ks], acc[q * 2 + mm][n], 0, 0, 0);
      __builtin_amdgcn_s_setprio(0);
      __builtin_amdgcn_s_barrier();
    }
    // tile boundary: own loads (issued phases 0-1) are the only in-flight VMEM
    asm volatile("s_waitcnt vmcnt(0)" ::: "memory");
    __builtin_amdgcn_s_barrier();
    cur ^= 1;
  }

  // epilogue: scatter q (pre-scaled), k(+s), v^T, gate
#pragma unroll
  for (int m = 0; m < 8; ++m) {
    const int gr0 = m0 + wr * 128 + m * 16 + l4 * 4;
    const int bb = gr0 >> 11;
    const int nn0 = gr0 & 2047;
#pragma unroll
    for (int n = 0; n < 4; ++n) {
      const int gc = n0 + wc * 64 + n * 16 + l15;
      if (gc < 3072) {
        const int t = gc >> 10, hd = gc & 1023;
        const int h = hd >> 6, d = hd & 63;
        const int base = ((bb * 16 + h) * 2048 + nn0) * 64 + d;
        if (t == 0) {
#pragma unroll
          for (int r = 0; r < 4; ++r)
            p.q[base + r * 64] = __float2bfloat16(acc[m][n][r] * QSCALE);
        } else if (t == 1) {
#pragma unroll
          for (int r = 0; r < 4; ++r)
            p.k[base + r * 64] =
                __float2bfloat16(acc[m][n][r] + __bfloat162float(p.sT[base + r * 64]));
        } else {
          union { bf16 h4[4]; s16x4 s; } u;
#pragma unroll
          for (int r = 0; r < 4; ++r) u.h4[r] = __float2bfloat16(acc[m][n][r]);
          *reinterpret_cast<s16x4*>(&p.vt[((bb * 16 + h) * 64 + d) * 2048 + nn0]) = u.s;
        }
      } else {
        const int gcc = gc - 3072;
#pragma unroll
        for (int r = 0; r < 4; ++r)
          p.gate[(gr0 + r) * 1024 + gcc] = __float2bfloat16(acc[m][n][r]);
      }
    }
  }
}

// ---------------- bf16 GEMM, 64x128 tile (for N=1024 GEMMs: 512 blocks = 2/CU) ----------------
template <int EPI>
__global__ __launch_bounds__(256) void gemm2_k(GemmP p) {
  constexpr int K = 1024;
  __shared__ bf16 As[64 * 32];
  __shared__ bf16 Bs[128 * 32];
  const int tid = threadIdx.x;
  const int wid = tid >> 6, lane = tid & 63;
  const int l15 = lane & 15, l4 = lane >> 4;
  const int wc = wid;  // 4 waves x (64M x 32N)
  const int m0 = blockIdx.y * 64, n0 = blockIdx.x * 128;
  const bf16* Arow = p.A + m0 * K;
  const bf16* Brow = p.B0 + n0 * K;

  f32x4 acc[4][2];
#pragma unroll
  for (int m = 0; m < 4; ++m)
#pragma unroll
    for (int n = 0; n < 2; ++n) acc[m][n] = zf4();

  const int srowA = tid >> 2, skc = tid & 3;  // A: 64 rows x 4 chunks
  for (int kt = 0; kt < K; kt += 32) {
    gl_lds16(Arow + srowA * K + kt + skc * 8, As + wid * 512);
#pragma unroll
    for (int it = 0; it < 2; ++it)
      gl_lds16(Brow + (it * 64 + srowA) * K + kt + skc * 8, Bs + it * 2048 + wid * 512);
    __syncthreads();
    bf16x8 af[4], bfr[2];
#pragma unroll
    for (int m = 0; m < 4; ++m)
      af[m] = *reinterpret_cast<const bf16x8*>(&As[(m * 16 + l15) * 32 + 8 * l4]);
#pragma unroll
    for (int n = 0; n < 2; ++n)
      bfr[n] = *reinterpret_cast<const bf16x8*>(&Bs[(wc * 32 + n * 16 + l15) * 32 + 8 * l4]);
#pragma unroll
    for (int m = 0; m < 4; ++m)
#pragma unroll
      for (int n = 0; n < 2; ++n)
        acc[m][n] = __builtin_amdgcn_mfma_f32_16x16x32_bf16(af[m], bfr[n], acc[m][n], 0, 0, 0);
    __syncthreads();
  }

#pragma unroll
  for (int m = 0; m < 4; ++m) {
    const int gr0 = m0 + m * 16 + l4 * 4;
    const int bb = gr0 >> 11;
    const int nn0 = gr0 & 2047;
#pragma unroll
    for (int n = 0; n < 2; ++n) {
      const int gc = n0 + wc * 32 + n * 16 + l15;
      if (EPI == 0) {
        const int h = gc >> 6, d = gc & 63;
        bf16* dst = p.obf + ((bb * 16 + h) * 2048 + nn0) * 64 + d;
#pragma unroll
        for (int r = 0; r < 4; ++r) dst[r * 64] = __float2bfloat16(acc[m][n][r]);
      } else {
        const float bias = p.bias[gc];
#pragma unroll
        for (int r = 0; r < 4; ++r) p.out[(gr0 + r) * 1024 + gc] = acc[m][n][r] + bias;
      }
    }
  }
}

// ---------------- flash attention (swapped-operand, in-register softmax) ----------------
__global__ __launch_bounds__(256) void flash_k(const bf16* __restrict__ qT,
                                               const bf16* __restrict__ kTb,
                                               const bf16* __restrict__ vTt,
                                               const bf16* __restrict__ gateb,
                                               bf16* __restrict__ attng) {
  __shared__ bf16 Ks[2][64 * 64];  // [key][d], XOR-swizzled 16B chunks, double-buffered
  __shared__ bf16 Vs[2][64 * 64];  // [d][key], XOR-swizzled 16B chunks, double-buffered
  const int tid = threadIdx.x;
  const int wid = tid >> 6, lane = tid & 63;
  const int l15 = lane & 15, l4 = lane >> 4;
  const int hbit = lane >> 5;  // bit5 of lane
  const int qt = blockIdx.x, bh = blockIdx.y;
  const int qr0 = qt * 64 + wid * 16;
  const bf16* qbase = qT + (bh * 2048 + qr0) * 64;
  const bf16x8 qf0 = *reinterpret_cast<const bf16x8*>(&qbase[l15 * 64 + 8 * l4]);
  const bf16x8 qf1 = *reinterpret_cast<const bf16x8*>(&qbase[l15 * 64 + 32 + 8 * l4]);
  const bf16* kbase = kTb + bh * 2048 * 64;
  const bf16* vbase = vTt + bh * 64 * 2048;
  const int srcQ0 = (((lane & 16) << 1) | (lane & 15)) << 2;
  const int srcQ1 = srcQ0 | 64;

  f32x4 o[4];  // O^T frags: o[nd][r] = O^T[d=nd*16+l4*4+r][qrow=l15]
#pragma unroll
  for (int i = 0; i < 4; ++i) o[i] = zf4();
  float mrun = -1e30f, lrun = 0.f;
  const int srow = tid >> 3, sc = tid & 7;

  auto stage = [&](int b, int kt) {
#pragma unroll
    for (int it = 0; it < 2; ++it) {
      const int row = it * 32 + srow;
      const int c2 = sc ^ (row & 7);  // pre-swizzled global source; LDS stays linear
      gl_lds16(kbase + (kt * 64 + row) * 64 + c2 * 8, &Ks[b][it * 2048 + wid * 512]);
      gl_lds16(vbase + row * 2048 + kt * 64 + c2 * 8, &Vs[b][it * 2048 + wid * 512]);
    }
  };

  stage(0, 0);
  __syncthreads();
  int cur = 0;

  for (int kt = 0; kt < 32; ++kt) {
    if (kt < 31) stage(cur ^ 1, kt + 1);  // prefetch in flight across compute

    // S^T = K Q^T (swapped): 16 keys/lane for q-row l15
    f32x4 sa[4];
#pragma unroll
    for (int n = 0; n < 4; ++n) sa[n] = zf4();
    __builtin_amdgcn_s_setprio(1);
#pragma unroll
    for (int kk = 0; kk < 2; ++kk) {
      const bf16x8 qv = kk ? qf1 : qf0;
#pragma unroll
      for (int n = 0; n < 4; ++n) {
        const int key = n * 16 + l15;
        const bf16x8 kv = *reinterpret_cast<const bf16x8*>(
            &Ks[cur][key * 64 + ((kk * 4 + l4) ^ (key & 7)) * 8]);
        sa[n] = __builtin_amdgcn_mfma_f32_16x16x32_bf16(kv, qv, sa[n], 0, 0, 0);
      }
    }
    __builtin_amdgcn_s_setprio(0);

    // row max: in-lane 16 + 2 shfl rounds
    float mt = sa[0][0];
#pragma unroll
    for (int n = 0; n < 4; ++n)
#pragma unroll
      for (int r = 0; r < 4; ++r) mt = fmaxf(mt, sa[n][r]);
    mt = fmaxf(mt, __shfl_xor(mt, 16, 64));
    mt = fmaxf(mt, __shfl_xor(mt, 32, 64));

    // T13 defer-max
    const bool upd = !__all(mt <= mrun + RESCALE_THR);
    float fac = 1.f;
    if (upd) {
      const float mn = fmaxf(mrun, mt);
      fac = fexp2(mrun - mn);
      mrun = mn;
    }

    float p[4][4];
    float psum = 0.f;
#pragma unroll
    for (int n = 0; n < 4; ++n)
#pragma unroll
      for (int r = 0; r < 4; ++r) {
        p[n][r] = fexp2(sa[n][r] - mrun);
        psum += p[n][r];
      }
    psum += __shfl_xor(psum, 16, 64);
    psum += __shfl_xor(psum, 32, 64);
    if (upd) {
      lrun = lrun * fac + psum;
#pragma unroll
      for (int nd = 0; nd < 4; ++nd)
#pragma unroll
        for (int r = 0; r < 4; ++r) o[nd][r] *= fac;
    } else {
      lrun += psum;
    }

    // pack P to bf16 pairs
    int Cp[4][2];
#pragma unroll
    for (int n = 0; n < 4; ++n) {
      Cp[n][0] = (int)cvt_pk_bf16(p[n][0], p[n][1]);
      Cp[n][1] = (int)cvt_pk_bf16(p[n][2], p[n][3]);
    }

    // O^T += V^T P^T : pa via bpermute
    __builtin_amdgcn_s_setprio(1);
#pragma unroll
    for (int kk = 0; kk < 2; ++kk) {
      const int x0 = __builtin_amdgcn_ds_bpermute(srcQ0, Cp[2 * kk][0]);
      const int x1 = __builtin_amdgcn_ds_bpermute(srcQ0, Cp[2 * kk + 1][0]);
      const int y0 = __builtin_amdgcn_ds_bpermute(srcQ0, Cp[2 * kk][1]);
      const int y1 = __builtin_amdgcn_ds_bpermute(srcQ0, Cp[2 * kk + 1][1]);
      const int z0 = __builtin_amdgcn_ds_bpermute(srcQ1, Cp[2 * kk][0]);
      const int z1 = __builtin_amdgcn_ds_bpermute(srcQ1, Cp[2 * kk + 1][0]);
      const int t0 = __builtin_amdgcn_ds_bpermute(srcQ1, Cp[2 * kk][1]);
      const int t1 = __builtin_amdgcn_ds_bpermute(srcQ1, Cp[2 * kk + 1][1]);
      union { int u[4]; bf16x8 v; } pw;
      pw.u[0] = hbit ? x1 : x0;
      pw.u[1] = hbit ? y1 : y0;
      pw.u[2] = hbit ? z1 : z0;
      pw.u[3] = hbit ? t1 : t0;
#pragma unroll
      for (int nd = 0; nd < 4; ++nd) {
        const int d = nd * 16 + l15;
        const bf16x8 vv = *reinterpret_cast<const bf16x8*>(
            &Vs[cur][d * 64 + ((kk * 4 + l4) ^ (d & 7)) * 8]);
        o[nd] = __builtin_amdgcn_mfma_f32_16x16x32_bf16(vv, pw.v, o[nd], 0, 0, 0);
      }
    }
    __builtin_amdgcn_s_setprio(0);

    __syncthreads();  // drains prefetch + guards buffer swap
    cur ^= 1;
  }

  const int bb = bh >> 4, h = bh & 15;
  const int grow = bb * 2048 + qr0 + l15;
  const float inv = 1.0f / lrun;
#pragma unroll
  for (int nd = 0; nd < 4; ++nd) {
    const int gi = grow * 1024 + h * 64 + nd * 16 + l4 * 4;
    union { s16x4 s; bf16 h4[4]; } gu, ou;
    gu.s = *reinterpret_cast<const s16x4*>(&gateb[gi]);
#pragma unroll
    for (int r = 0; r < 4; ++r)
      ou.h4[r] = __float2bfloat16(o[nd][r] * inv * __bfloat162float(gu.h4[r]));
    *reinterpret_cast<s16x4*>(&attng[gi]) = ou.s;
  }
}

// ---------------- launcher ----------------
extern "C" void kernel_launch(void* const* d_in, const int* in_sizes, int n_in,
                              void* d_out, int out_size, void* d_ws, size_t ws_size,
                              hipStream_t stream) {
  const float* x = (const float*)d_in[0];
  const float* e = (const float*)d_in[1];
  const float* Wqkv = (const float*)d_in[2];
  const float* Ws = (const float*)d_in[3];
  const float* Wgate = (const float*)d_in[4];
  const float* Wproj = (const float*)d_in[5];
  const float* bproj = (const float*)d_in[6];
  float* out = (float*)d_out;

  char* w = (char*)d_ws;
  auto carve = [&](size_t bytes) -> void* {
    void* p = (void*)w;
    w += (bytes + 255) & ~size_t(255);
    return p;
  };
  // time-disjoint aliases: qT overlays ebf (ebf dead after gemm2<0>);
  // attng overlays sT (sT dead after gemm256).
  bf16* xbf    = (bf16*)carve(4096UL * 1024 * 2);
  bf16* ebf    = (bf16*)carve(4096UL * 1024 * 2);
  bf16* Wqkvt  = (bf16*)carve(3072UL * 1024 * 2);
  bf16* Wst    = (bf16*)carve(1024UL * 1024 * 2);
  bf16* Wgatet = (bf16*)carve(1024UL * 1024 * 2);
  bf16* Wprojt = (bf16*)carve(1024UL * 1024 * 2);
  bf16* kTb    = (bf16*)carve(32UL * 2048 * 64 * 2);
  bf16* vTt    = (bf16*)carve(32UL * 64 * 2048 * 2);
  bf16* sT     = (bf16*)carve(32UL * 2048 * 64 * 2);
  bf16* gateb  = (bf16*)carve(4096UL * 1024 * 2);
  bf16* qT     = ebf;
  bf16* attng  = sT;

  conv_bf16_k<<<4096, 256, 0, stream>>>(x, xbf, 1048576);
  conv_bf16_k<<<4096, 256, 0, stream>>>(e, ebf, 1048576);
  transp_k<<<dim3(96, 32), dim3(32, 8), 0, stream>>>(Wqkv, Wqkvt, 1024, 3072);
  transp_k<<<dim3(32, 32), dim3(32, 8), 0, stream>>>(Ws, Wst, 1024, 1024);
  transp_k<<<dim3(32, 32), dim3(32, 8), 0, stream>>>(Wgate, Wgatet, 1024, 1024);
  transp_k<<<dim3(32, 32), dim3(32, 8), 0, stream>>>(Wproj, Wprojt, 1024, 1024);

  GemmP ps{};
  ps.A = ebf; ps.B0 = Wst; ps.obf = sT;
  gemm2_k<0><<<dim3(8, 64), 256, 0, stream>>>(ps);

  GemmP pq{};
  pq.A = xbf; pq.B0 = Wqkvt; pq.B1 = Wgatet; pq.sT = sT;
  pq.q = qT; pq.k = kTb; pq.vt = vTt; pq.gate = gateb;
  gemm256_k<<<dim3(16, 16), 512, 0, stream>>>(pq);

  flash_k<<<dim3(32, 32), 256, 0, stream>>>(qT, kTb, vTt, gateb, attng);

  GemmP pp{};
  pp.A = attng; pp.B0 = Wprojt; pp.out = out; pp.bias = bproj;
  gemm2_k<2><<<dim3(8, 64), 256, 0, stream>>>(pp);
}

// Round 6
// 268.700 us; speedup vs baseline: 1.3333x; 1.0408x over previous
//
#include <hip/hip_runtime.h>
#include <hip/hip_bf16.h>

#define SCALE 0.125f
#define QSCALE 0.18033688f  // SCALE * log2(e): q pre-scaled -> softmax in log2 domain
#define RESCALE_THR 8.0f    // T13 defer-max threshold (log2 units, P bounded by 2^8)

typedef __attribute__((ext_vector_type(8))) __bf16 bf16x8;
typedef __attribute__((ext_vector_type(4))) float f32x4;
typedef __attribute__((ext_vector_type(4))) short s16x4;
typedef __hip_bfloat16 bf16;

__device__ __forceinline__ void gl_lds16(const bf16* g, bf16* l) {
  __builtin_amdgcn_global_load_lds(
      (const __attribute__((address_space(1))) void*)g,
      (__attribute__((address_space(3))) void*)l, 16, 0, 0);
}

__device__ __forceinline__ float fexp2(float x) {
#if __has_builtin(__builtin_amdgcn_exp2f)
  return __builtin_amdgcn_exp2f(x);
#else
  return exp2f(x);
#endif
}

__device__ __forceinline__ unsigned cvt_pk_bf16(float lo, float hi) {
  unsigned r;
  asm("v_cvt_pk_bf16_f32 %0, %1, %2" : "=v"(r) : "v"(lo), "v"(hi));
  return r;
}

__device__ __forceinline__ f32x4 zf4() {
  f32x4 v; v[0] = 0.f; v[1] = 0.f; v[2] = 0.f; v[3] = 0.f; return v;
}

// ---------------- fp32 -> bf16 copy, x and e fused (1 launch) ----------------
__global__ __launch_bounds__(256) void conv2_bf16_k(const float* __restrict__ a,
                                                    const float* __restrict__ b,
                                                    bf16* __restrict__ oa,
                                                    bf16* __restrict__ ob) {
  const int bi = blockIdx.x;
  const float* in = (bi < 4096) ? a : b;
  bf16* out = (bi < 4096) ? oa : ob;
  const int i = ((bi < 4096) ? bi : bi - 4096) * 256 + threadIdx.x;
  const float4 v = reinterpret_cast<const float4*>(in)[i];
  union { bf16 h4[4]; s16x4 s; } u;
  u.h4[0] = __float2bfloat16(v.x);
  u.h4[1] = __float2bfloat16(v.y);
  u.h4[2] = __float2bfloat16(v.z);
  u.h4[3] = __float2bfloat16(v.w);
  reinterpret_cast<s16x4*>(out)[i] = u.s;
}

// ---------------- all 4 weight transposes in one launch ----------------
struct TranspP { const float* s[4]; bf16* d[4]; };
__global__ __launch_bounds__(256) void transp_all_k(TranspP tp) {
  __shared__ float t[32][33];
  const int z = blockIdx.z;
  const int j = (z < 3) ? 0 : z - 2;
  const int coff = (z < 3) ? (z << 10) : 0;
  const int Nsrc = (j == 0) ? 3072 : 1024;
  const float* W = tp.s[j];
  bf16* dst = tp.d[j] + (size_t)((z < 3) ? z : 0) * 1024 * 1024;
  const int tx = threadIdx.x, ty = threadIdx.y;
  const int n0 = blockIdx.x * 32, k0 = blockIdx.y * 32;
#pragma unroll
  for (int i = 0; i < 4; ++i)
    t[ty + 8 * i][tx] = W[(k0 + ty + 8 * i) * Nsrc + coff + n0 + tx];
  __syncthreads();
#pragma unroll
  for (int i = 0; i < 4; ++i)
    dst[(n0 + ty + 8 * i) * 1024 + k0 + tx] = __float2bfloat16(t[tx][ty + 8 * i]);
}

struct GemmP {
  const bf16* A;    // [M][1024] row-major
  const bf16* B0;   // Bt [N][1024]
  const bf16* B1;   // gate weights Bt
  const bf16* sT;   // s in [B,H,N,D]
  bf16 *q, *k, *vt, *gate, *obf;
  float* out;
  const float* bias;
};

// ---------------- 256x256 4-phase bf16 GEMM (qkv+gate), BK=64, 8 waves ----------------
__global__ __launch_bounds__(512, 2) void gemm256_k(GemmP p) {
  constexpr int K = 1024;
  constexpr int NT = 16;  // K / 64
  __shared__ bf16 AB[2][2][256 * 64];  // [buf][A/B][row*64+col]
  const int tid = threadIdx.x;
  const int wid = tid >> 6, lane = tid & 63;
  const int l15 = lane & 15, l4 = lane >> 4;
  const int wr = wid >> 2, wc = wid & 3;  // 2x4 waves, each 128x64 output

  // XCD-bijective swizzle of 256 blocks (256 % 8 == 0)
  const int bid0 = blockIdx.y * 16 + blockIdx.x;
  const int bid = (bid0 & 7) * 32 + (bid0 >> 3);
  const int m0 = (bid >> 4) * 256, n0 = (bid & 15) * 256;

  const bf16* Arow = p.A + (size_t)m0 * K;
  const bf16* Brow = (n0 >= 3072) ? p.B1 + (size_t)(n0 - 3072) * K
                                  : p.B0 + (size_t)n0 * K;

  f32x4 acc[8][4];
#pragma unroll
  for (int m = 0; m < 8; ++m)
#pragma unroll
    for (int n = 0; n < 4; ++n) acc[m][n] = zf4();

  const int srow = tid >> 3, sc = tid & 7;
  auto stageA = [&](int b, int kt) {
#pragma unroll
    for (int s = 0; s < 4; ++s) {
      const int r = s * 64 + srow;
      const int c2 = sc ^ (r & 7);
      gl_lds16(Arow + (size_t)r * K + kt * 64 + c2 * 8, &AB[b][0][r * 64 + sc * 8]);
    }
  };
  auto stageB = [&](int b, int kt) {
#pragma unroll
    for (int s = 0; s < 4; ++s) {
      const int r = s * 64 + srow;
      const int c2 = sc ^ (r & 7);
      gl_lds16(Brow + (size_t)r * K + kt * 64 + c2 * 8, &AB[b][1][r * 64 + sc * 8]);
    }
  };

  stageA(0, 0);
  stageB(0, 0);
  __syncthreads();
  int cur = 0;

  for (int kt = 0; kt < NT; ++kt) {
    bf16x8 bfv[4][2];
#pragma unroll
    for (int q = 0; q < 4; ++q) {
      bf16x8 af[2][2];
#pragma unroll
      for (int mm = 0; mm < 2; ++mm) {
        const int row = wr * 128 + (q * 2 + mm) * 16 + l15;
#pragma unroll
        for (int ks = 0; ks < 2; ++ks)
          af[mm][ks] = *reinterpret_cast<const bf16x8*>(
              &AB[cur][0][row * 64 + ((ks * 4 + l4) ^ (row & 7)) * 8]);
      }
      if (q == 0) {
#pragma unroll
        for (int n = 0; n < 4; ++n) {
          const int row = wc * 64 + n * 16 + l15;
#pragma unroll
          for (int ks = 0; ks < 2; ++ks)
            bfv[n][ks] = *reinterpret_cast<const bf16x8*>(
                &AB[cur][1][row * 64 + ((ks * 4 + l4) ^ (row & 7)) * 8]);
        }
      }
      if (q == 0 && kt + 1 < NT) stageA(cur ^ 1, kt + 1);
      if (q == 1 && kt + 1 < NT) stageB(cur ^ 1, kt + 1);

      __builtin_amdgcn_s_barrier();
      __builtin_amdgcn_s_setprio(1);
#pragma unroll
      for (int mm = 0; mm < 2; ++mm)
#pragma unroll
        for (int n = 0; n < 4; ++n)
#pragma unroll
          for (int ks = 0; ks < 2; ++ks)
            acc[q * 2 + mm][n] = __builtin_amdgcn_mfma_f32_16x16x32_bf16(
                af[mm][ks], bfv[n][ks], acc[q * 2 + mm][n], 0, 0, 0);
      __builtin_amdgcn_s_setprio(0);
      __builtin_amdgcn_s_barrier();
    }
    asm volatile("s_waitcnt vmcnt(0)" ::: "memory");
    __builtin_amdgcn_s_barrier();
    cur ^= 1;
  }

#pragma unroll
  for (int m = 0; m < 8; ++m) {
    const int gr0 = m0 + wr * 128 + m * 16 + l4 * 4;
    const int bb = gr0 >> 11;
    const int nn0 = gr0 & 2047;
#pragma unroll
    for (int n = 0; n < 4; ++n) {
      const int gc = n0 + wc * 64 + n * 16 + l15;
      if (gc < 3072) {
        const int t = gc >> 10, hd = gc & 1023;
        const int h = hd >> 6, d = hd & 63;
        const int base = ((bb * 16 + h) * 2048 + nn0) * 64 + d;
        if (t == 0) {
#pragma unroll
          for (int r = 0; r < 4; ++r)
            p.q[base + r * 64] = __float2bfloat16(acc[m][n][r] * QSCALE);
        } else if (t == 1) {
#pragma unroll
          for (int r = 0; r < 4; ++r)
            p.k[base + r * 64] =
                __float2bfloat16(acc[m][n][r] + __bfloat162float(p.sT[base + r * 64]));
        } else {
          union { bf16 h4[4]; s16x4 s; } u;
#pragma unroll
          for (int r = 0; r < 4; ++r) u.h4[r] = __float2bfloat16(acc[m][n][r]);
          *reinterpret_cast<s16x4*>(&p.vt[((bb * 16 + h) * 64 + d) * 2048 + nn0]) = u.s;
        }
      } else {
        const int gcc = gc - 3072;
#pragma unroll
        for (int r = 0; r < 4; ++r)
          p.gate[(gr0 + r) * 1024 + gcc] = __float2bfloat16(acc[m][n][r]);
      }
    }
  }
}

// ---------------- bf16 GEMM, 64x128 tile (N=1024 GEMMs: 512 blocks = 2/CU) ----------------
template <int EPI>
__global__ __launch_bounds__(256) void gemm2_k(GemmP p) {
  constexpr int K = 1024;
  __shared__ bf16 As[64 * 32];
  __shared__ bf16 Bs[128 * 32];
  const int tid = threadIdx.x;
  const int wid = tid >> 6, lane = tid & 63;
  const int l15 = lane & 15, l4 = lane >> 4;
  const int wc = wid;
  const int m0 = blockIdx.y * 64, n0 = blockIdx.x * 128;
  const bf16* Arow = p.A + m0 * K;
  const bf16* Brow = p.B0 + n0 * K;

  f32x4 acc[4][2];
#pragma unroll
  for (int m = 0; m < 4; ++m)
#pragma unroll
    for (int n = 0; n < 2; ++n) acc[m][n] = zf4();

  const int srowA = tid >> 2, skc = tid & 3;
  for (int kt = 0; kt < K; kt += 32) {
    gl_lds16(Arow + srowA * K + kt + skc * 8, As + wid * 512);
#pragma unroll
    for (int it = 0; it < 2; ++it)
      gl_lds16(Brow + (it * 64 + srowA) * K + kt + skc * 8, Bs + it * 2048 + wid * 512);
    __syncthreads();
    bf16x8 af[4], bfr[2];
#pragma unroll
    for (int m = 0; m < 4; ++m)
      af[m] = *reinterpret_cast<const bf16x8*>(&As[(m * 16 + l15) * 32 + 8 * l4]);
#pragma unroll
    for (int n = 0; n < 2; ++n)
      bfr[n] = *reinterpret_cast<const bf16x8*>(&Bs[(wc * 32 + n * 16 + l15) * 32 + 8 * l4]);
#pragma unroll
    for (int m = 0; m < 4; ++m)
#pragma unroll
      for (int n = 0; n < 2; ++n)
        acc[m][n] = __builtin_amdgcn_mfma_f32_16x16x32_bf16(af[m], bfr[n], acc[m][n], 0, 0, 0);
    __syncthreads();
  }

#pragma unroll
  for (int m = 0; m < 4; ++m) {
    const int gr0 = m0 + m * 16 + l4 * 4;
    const int bb = gr0 >> 11;
    const int nn0 = gr0 & 2047;
#pragma unroll
    for (int n = 0; n < 2; ++n) {
      const int gc = n0 + wc * 32 + n * 16 + l15;
      if (EPI == 0) {
        const int h = gc >> 6, d = gc & 63;
        bf16* dst = p.obf + ((bb * 16 + h) * 2048 + nn0) * 64 + d;
#pragma unroll
        for (int r = 0; r < 4; ++r) dst[r * 64] = __float2bfloat16(acc[m][n][r]);
      } else {
        const float bias = p.bias[gc];
#pragma unroll
        for (int r = 0; r < 4; ++r) p.out[(gr0 + r) * 1024 + gc] = acc[m][n][r] + bias;
      }
    }
  }
}

// ---------------- flash attention: 32 q-rows/wave, K/V frags reused x2 ----------------
// qT: [BH][N][D] bf16 pre-scaled by QSCALE. kTb: [BH][N][D] (k+s). vTt: [BH][D][N].
// Swapped QK: sa[g][n] = mfma(K,Q_g) -> lane holds S^T[key=n*16+l4*4+r][qrow=g*16+l15].
__global__ __launch_bounds__(256) void flash_k(const bf16* __restrict__ qT,
                                               const bf16* __restrict__ kTb,
                                               const bf16* __restrict__ vTt,
                                               const bf16* __restrict__ gateb,
                                               bf16* __restrict__ attng) {
  __shared__ bf16 Ks[2][64 * 64];  // [key][d], XOR-swizzled 16B chunks, dbuf
  __shared__ bf16 Vs[2][64 * 64];  // [d][key], XOR-swizzled 16B chunks, dbuf
  const int tid = threadIdx.x;
  const int wid = tid >> 6, lane = tid & 63;
  const int l15 = lane & 15, l4 = lane >> 4;
  const int hbit = lane >> 5;
  const int qt = blockIdx.x, bh = blockIdx.y;
  const int qr0 = qt * 128 + wid * 32;  // 32 q-rows per wave
  const bf16* qbase = qT + (bh * 2048 + qr0) * 64;
  bf16x8 qf[2][2];
#pragma unroll
  for (int g = 0; g < 2; ++g)
#pragma unroll
    for (int kk = 0; kk < 2; ++kk)
      qf[g][kk] = *reinterpret_cast<const bf16x8*>(
          &qbase[(g * 16 + l15) * 64 + kk * 32 + 8 * l4]);
  const bf16* kbase = kTb + bh * 2048 * 64;
  const bf16* vbase = vTt + bh * 64 * 2048;
  const int srcQ0 = (((lane & 16) << 1) | (lane & 15)) << 2;
  const int srcQ1 = srcQ0 | 64;

  f32x4 o[2][4];  // o[g][nd][r] = O^T[d=nd*16+l4*4+r][qrow=g*16+l15]
#pragma unroll
  for (int g = 0; g < 2; ++g)
#pragma unroll
    for (int i = 0; i < 4; ++i) o[g][i] = zf4();
  float mrun[2] = {-1e30f, -1e30f}, lrun[2] = {0.f, 0.f};
  const int srow = tid >> 3, sc = tid & 7;

  auto stage = [&](int b, int kt) {
#pragma unroll
    for (int it = 0; it < 2; ++it) {
      const int row = it * 32 + srow;
      const int c2 = sc ^ (row & 7);  // pre-swizzled global source; LDS linear
      gl_lds16(kbase + (kt * 64 + row) * 64 + c2 * 8, &Ks[b][it * 2048 + wid * 512]);
      gl_lds16(vbase + row * 2048 + kt * 64 + c2 * 8, &Vs[b][it * 2048 + wid * 512]);
    }
  };

  stage(0, 0);
  __syncthreads();
  int cur = 0;

  for (int kt = 0; kt < 32; ++kt) {
    if (kt < 31) stage(cur ^ 1, kt + 1);  // prefetch in flight across compute

    // S^T = K Q^T for both q-groups; K frags read ONCE, used twice
    f32x4 sa[2][4];
#pragma unroll
    for (int g = 0; g < 2; ++g)
#pragma unroll
      for (int n = 0; n < 4; ++n) sa[g][n] = zf4();
    __builtin_amdgcn_s_setprio(1);
#pragma unroll
    for (int kk = 0; kk < 2; ++kk) {
#pragma unroll
      for (int n = 0; n < 4; ++n) {
        const int key = n * 16 + l15;
        const bf16x8 kv = *reinterpret_cast<const bf16x8*>(
            &Ks[cur][key * 64 + ((kk * 4 + l4) ^ (key & 7)) * 8]);
#pragma unroll
        for (int g = 0; g < 2; ++g)
          sa[g][n] = __builtin_amdgcn_mfma_f32_16x16x32_bf16(kv, qf[g][kk], sa[g][n], 0, 0, 0);
      }
    }
    __builtin_amdgcn_s_setprio(0);

    // row max per q-group: in-lane 16 + shfl(16,32)
    float mt[2];
#pragma unroll
    for (int g = 0; g < 2; ++g) {
      float m = sa[g][0][0];
#pragma unroll
      for (int n = 0; n < 4; ++n)
#pragma unroll
        for (int r = 0; r < 4; ++r) m = fmaxf(m, sa[g][n][r]);
      m = fmaxf(m, __shfl_xor(m, 16, 64));
      mt[g] = fmaxf(m, __shfl_xor(m, 32, 64));
    }

    // T13 defer-max (joint wave-uniform decision)
    const int okg = (mt[0] <= mrun[0] + RESCALE_THR) & (mt[1] <= mrun[1] + RESCALE_THR);
    const bool upd = !__all(okg);
    float fac[2] = {1.f, 1.f};
    if (upd) {
#pragma unroll
      for (int g = 0; g < 2; ++g) {
        const float mn = fmaxf(mrun[g], mt[g]);
        fac[g] = fexp2(mrun[g] - mn);
        mrun[g] = mn;
      }
    }

    int Cp[2][4][2];
#pragma unroll
    for (int g = 0; g < 2; ++g) {
      float psum = 0.f;
      float p[4][4];
#pragma unroll
      for (int n = 0; n < 4; ++n)
#pragma unroll
        for (int r = 0; r < 4; ++r) {
          p[n][r] = fexp2(sa[g][n][r] - mrun[g]);
          psum += p[n][r];
        }
      psum += __shfl_xor(psum, 16, 64);
      psum += __shfl_xor(psum, 32, 64);
      if (upd) {
        lrun[g] = lrun[g] * fac[g] + psum;
#pragma unroll
        for (int nd = 0; nd < 4; ++nd)
#pragma unroll
          for (int r = 0; r < 4; ++r) o[g][nd][r] *= fac[g];
      } else {
        lrun[g] += psum;
      }
#pragma unroll
      for (int n = 0; n < 4; ++n) {
        Cp[g][n][0] = (int)cvt_pk_bf16(p[n][0], p[n][1]);
        Cp[g][n][1] = (int)cvt_pk_bf16(p[n][2], p[n][3]);
      }
    }

    // O^T += V^T P^T ; V frags read ONCE per kk, used for both q-groups
    __builtin_amdgcn_s_setprio(1);
#pragma unroll
    for (int kk = 0; kk < 2; ++kk) {
      bf16x8 pw[2];
#pragma unroll
      for (int g = 0; g < 2; ++g) {
        const int x0 = __builtin_amdgcn_ds_bpermute(srcQ0, Cp[g][2 * kk][0]);
        const int x1 = __builtin_amdgcn_ds_bpermute(srcQ0, Cp[g][2 * kk + 1][0]);
        const int y0 = __builtin_amdgcn_ds_bpermute(srcQ0, Cp[g][2 * kk][1]);
        const int y1 = __builtin_amdgcn_ds_bpermute(srcQ0, Cp[g][2 * kk + 1][1]);
        const int z0 = __builtin_amdgcn_ds_bpermute(srcQ1, Cp[g][2 * kk][0]);
        const int z1 = __builtin_amdgcn_ds_bpermute(srcQ1, Cp[g][2 * kk + 1][0]);
        const int t0 = __builtin_amdgcn_ds_bpermute(srcQ1, Cp[g][2 * kk][1]);
        const int t1 = __builtin_amdgcn_ds_bpermute(srcQ1, Cp[g][2 * kk + 1][1]);
        union { int u[4]; bf16x8 v; } u;
        u.u[0] = hbit ? x1 : x0;
        u.u[1] = hbit ? y1 : y0;
        u.u[2] = hbit ? z1 : z0;
        u.u[3] = hbit ? t1 : t0;
        pw[g] = u.v;
      }
#pragma unroll
      for (int nd = 0; nd < 4; ++nd) {
        const int d = nd * 16 + l15;
        const bf16x8 vv = *reinterpret_cast<const bf16x8*>(
            &Vs[cur][d * 64 + ((kk * 4 + l4) ^ (d & 7)) * 8]);
#pragma unroll
        for (int g = 0; g < 2; ++g)
          o[g][nd] = __builtin_amdgcn_mfma_f32_16x16x32_bf16(vv, pw[g], o[g][nd], 0, 0, 0);
      }
    }
    __builtin_amdgcn_s_setprio(0);

    __syncthreads();  // drains prefetch + guards buffer swap
    cur ^= 1;
  }

  const int bb = bh >> 4, h = bh & 15;
#pragma unroll
  for (int g = 0; g < 2; ++g) {
    const int grow = bb * 2048 + qr0 + g * 16 + l15;
    const float inv = 1.0f / lrun[g];
#pragma unroll
    for (int nd = 0; nd < 4; ++nd) {
      const int gi = grow * 1024 + h * 64 + nd * 16 + l4 * 4;
      union { s16x4 s; bf16 h4[4]; } gu, ou;
      gu.s = *reinterpret_cast<const s16x4*>(&gateb[gi]);
#pragma unroll
      for (int r = 0; r < 4; ++r)
        ou.h4[r] = __float2bfloat16(o[g][nd][r] * inv * __bfloat162float(gu.h4[r]));
      *reinterpret_cast<s16x4*>(&attng[gi]) = ou.s;
    }
  }
}

// ---------------- launcher ----------------
extern "C" void kernel_launch(void* const* d_in, const int* in_sizes, int n_in,
                              void* d_out, int out_size, void* d_ws, size_t ws_size,
                              hipStream_t stream) {
  const float* x = (const float*)d_in[0];
  const float* e = (const float*)d_in[1];
  const float* Wqkv = (const float*)d_in[2];
  const float* Ws = (const float*)d_in[3];
  const float* Wgate = (const float*)d_in[4];
  const float* Wproj = (const float*)d_in[5];
  const float* bproj = (const float*)d_in[6];
  float* out = (float*)d_out;

  char* w = (char*)d_ws;
  auto carve = [&](size_t bytes) -> void* {
    void* p = (void*)w;
    w += (bytes + 255) & ~size_t(255);
    return p;
  };
  // time-disjoint aliases: qT overlays ebf (dead after gemm2<0>);
  // attng overlays sT (dead after gemm256).
  bf16* xbf    = (bf16*)carve(4096UL * 1024 * 2);
  bf16* ebf    = (bf16*)carve(4096UL * 1024 * 2);
  bf16* Wqkvt  = (bf16*)carve(3072UL * 1024 * 2);
  bf16* Wst    = (bf16*)carve(1024UL * 1024 * 2);
  bf16* Wgatet = (bf16*)carve(1024UL * 1024 * 2);
  bf16* Wprojt = (bf16*)carve(1024UL * 1024 * 2);
  bf16* kTb    = (bf16*)carve(32UL * 2048 * 64 * 2);
  bf16* vTt    = (bf16*)carve(32UL * 64 * 2048 * 2);
  bf16* sT     = (bf16*)carve(32UL * 2048 * 64 * 2);
  bf16* gateb  = (bf16*)carve(4096UL * 1024 * 2);
  bf16* qT     = ebf;
  bf16* attng  = sT;

  conv2_bf16_k<<<8192, 256, 0, stream>>>(x, e, xbf, ebf);

  TranspP tp{};
  tp.s[0] = Wqkv; tp.s[1] = Ws; tp.s[2] = Wgate; tp.s[3] = Wproj;
  tp.d[0] = Wqkvt; tp.d[1] = Wst; tp.d[2] = Wgatet; tp.d[3] = Wprojt;
  transp_all_k<<<dim3(32, 32, 6), dim3(32, 8), 0, stream>>>(tp);

  GemmP ps{};
  ps.A = ebf; ps.B0 = Wst; ps.obf = sT;
  gemm2_k<0><<<dim3(8, 64), 256, 0, stream>>>(ps);

  GemmP pq{};
  pq.A = xbf; pq.B0 = Wqkvt; pq.B1 = Wgatet; pq.sT = sT;
  pq.q = qT; pq.k = kTb; pq.vt = vTt; pq.gate = gateb;
  gemm256_k<<<dim3(16, 16), 512, 0, stream>>>(pq);

  flash_k<<<dim3(16, 32), 256, 0, stream>>>(qT, kTb, vTt, gateb, attng);

  GemmP pp{};
  pp.A = attng; pp.B0 = Wprojt; pp.out = out; pp.bias = bproj;
  gemm2_k<2><<<dim3(8, 64), 256, 0, stream>>>(pp);
}

// Round 8
// 267.898 us; speedup vs baseline: 1.3373x; 1.0030x over previous
//
#include <hip/hip_runtime.h>
#include <hip/hip_bf16.h>

#define SCALE 0.125f
#define QSCALE 0.18033688f  // SCALE * log2(e): q pre-scaled -> softmax in log2 domain
#define RESCALE_THR 8.0f    // T13 defer-max threshold (log2 units, P bounded by 2^8)

typedef __attribute__((ext_vector_type(8))) __bf16 bf16x8;
typedef __attribute__((ext_vector_type(4))) float f32x4;
typedef __attribute__((ext_vector_type(4))) short s16x4;
typedef __hip_bfloat16 bf16;

__device__ __forceinline__ void gl_lds16(const bf16* g, bf16* l) {
  __builtin_amdgcn_global_load_lds(
      (const __attribute__((address_space(1))) void*)g,
      (__attribute__((address_space(3))) void*)l, 16, 0, 0);
}

__device__ __forceinline__ float fexp2(float x) {
#if __has_builtin(__builtin_amdgcn_exp2f)
  return __builtin_amdgcn_exp2f(x);
#else
  return exp2f(x);
#endif
}

__device__ __forceinline__ unsigned cvt_pk_bf16(float lo, float hi) {
  unsigned r;
  asm("v_cvt_pk_bf16_f32 %0, %1, %2" : "=v"(r) : "v"(lo), "v"(hi));
  return r;
}

__device__ __forceinline__ f32x4 zf4() {
  f32x4 v; v[0] = 0.f; v[1] = 0.f; v[2] = 0.f; v[3] = 0.f; return v;
}

// ---------------- fused prep: 4 weight transposes (z<6) + x/e bf16 convert (z==6) ----------------
struct PrepP { const float* s[4]; bf16* d[4]; const float *x, *e; bf16 *xb, *eb; };
__global__ __launch_bounds__(256) void prep_k(PrepP tp) {
  const int tid = threadIdx.x;
  const int z = blockIdx.z;
  if (z == 6) {
    // conv: 262144 threads x 8 float4 = 2M float4 (1M x + 1M e)
    const int i = (blockIdx.y * 32 + blockIdx.x) * 256 + tid;
#pragma unroll
    for (int u = 0; u < 8; ++u) {
      const int idx = u * 262144 + i;
      const bool isx = idx < 1048576;
      const int k = isx ? idx : idx - 1048576;
      const float4 v = reinterpret_cast<const float4*>(isx ? tp.x : tp.e)[k];
      union { bf16 h4[4]; s16x4 s; } u4;
      u4.h4[0] = __float2bfloat16(v.x);
      u4.h4[1] = __float2bfloat16(v.y);
      u4.h4[2] = __float2bfloat16(v.z);
      u4.h4[3] = __float2bfloat16(v.w);
      reinterpret_cast<s16x4*>(isx ? tp.xb : tp.eb)[k] = u4.s;
    }
    return;
  }
  __shared__ float t[32][33];
  const int j = (z < 3) ? 0 : z - 2;
  const int coff = (z < 3) ? (z << 10) : 0;
  const int Nsrc = (j == 0) ? 3072 : 1024;
  const float* W = tp.s[j];
  bf16* dst = tp.d[j] + (size_t)((z < 3) ? z : 0) * 1024 * 1024;
  const int tx = tid & 31, ty = tid >> 5;
  const int n0 = blockIdx.x * 32, k0 = blockIdx.y * 32;
#pragma unroll
  for (int i = 0; i < 4; ++i)
    t[ty + 8 * i][tx] = W[(k0 + ty + 8 * i) * Nsrc + coff + n0 + tx];
  __syncthreads();
#pragma unroll
  for (int i = 0; i < 4; ++i)
    dst[(n0 + ty + 8 * i) * 1024 + k0 + tx] = __float2bfloat16(t[tx][ty + 8 * i]);
}

struct GemmP {
  const bf16* A;    // [M][1024] row-major
  const bf16* B0;   // Bt [N][1024]
  const bf16* B1;   // gate weights Bt
  const bf16* sT;   // s in [B,H,N,D]
  bf16 *q, *k, *vt, *gate, *obf;
  float* out;
  const float* bias;
};

// ---------------- 256x256 4-phase bf16 GEMM (qkv+gate), BK=64, 8 waves ----------------
__global__ __launch_bounds__(512, 2) void gemm256_k(GemmP p) {
  constexpr int K = 1024;
  constexpr int NT = 16;  // K / 64
  __shared__ bf16 AB[2][2][256 * 64];  // [buf][A/B][row*64+col]
  const int tid = threadIdx.x;
  const int wid = tid >> 6, lane = tid & 63;
  const int l15 = lane & 15, l4 = lane >> 4;
  const int wr = wid >> 2, wc = wid & 3;  // 2x4 waves, each 128x64 output

  const int bid0 = blockIdx.y * 16 + blockIdx.x;
  const int bid = (bid0 & 7) * 32 + (bid0 >> 3);  // XCD-bijective (256%8==0)
  const int m0 = (bid >> 4) * 256, n0 = (bid & 15) * 256;

  const bf16* Arow = p.A + (size_t)m0 * K;
  const bf16* Brow = (n0 >= 3072) ? p.B1 + (size_t)(n0 - 3072) * K
                                  : p.B0 + (size_t)n0 * K;

  f32x4 acc[8][4];
#pragma unroll
  for (int m = 0; m < 8; ++m)
#pragma unroll
    for (int n = 0; n < 4; ++n) acc[m][n] = zf4();

  const int srow = tid >> 3, sc = tid & 7;
  auto stageA = [&](int b, int kt) {
#pragma unroll
    for (int s = 0; s < 4; ++s) {
      const int r = s * 64 + srow;
      const int c2 = sc ^ (r & 7);
      gl_lds16(Arow + (size_t)r * K + kt * 64 + c2 * 8, &AB[b][0][r * 64 + sc * 8]);
    }
  };
  auto stageB = [&](int b, int kt) {
#pragma unroll
    for (int s = 0; s < 4; ++s) {
      const int r = s * 64 + srow;
      const int c2 = sc ^ (r & 7);
      gl_lds16(Brow + (size_t)r * K + kt * 64 + c2 * 8, &AB[b][1][r * 64 + sc * 8]);
    }
  };

  stageA(0, 0);
  stageB(0, 0);
  __syncthreads();
  int cur = 0;

  for (int kt = 0; kt < NT; ++kt) {
    bf16x8 bfv[4][2];
#pragma unroll
    for (int q = 0; q < 4; ++q) {
      bf16x8 af[2][2];
#pragma unroll
      for (int mm = 0; mm < 2; ++mm) {
        const int row = wr * 128 + (q * 2 + mm) * 16 + l15;
#pragma unroll
        for (int ks = 0; ks < 2; ++ks)
          af[mm][ks] = *reinterpret_cast<const bf16x8*>(
              &AB[cur][0][row * 64 + ((ks * 4 + l4) ^ (row & 7)) * 8]);
      }
      if (q == 0) {
#pragma unroll
        for (int n = 0; n < 4; ++n) {
          const int row = wc * 64 + n * 16 + l15;
#pragma unroll
          for (int ks = 0; ks < 2; ++ks)
            bfv[n][ks] = *reinterpret_cast<const bf16x8*>(
                &AB[cur][1][row * 64 + ((ks * 4 + l4) ^ (row & 7)) * 8]);
        }
      }
      if (q == 0 && kt + 1 < NT) stageA(cur ^ 1, kt + 1);
      if (q == 1 && kt + 1 < NT) stageB(cur ^ 1, kt + 1);

      __builtin_amdgcn_s_barrier();
      __builtin_amdgcn_s_setprio(1);
#pragma unroll
      for (int mm = 0; mm < 2; ++mm)
#pragma unroll
        for (int n = 0; n < 4; ++n)
#pragma unroll
          for (int ks = 0; ks < 2; ++ks)
            acc[q * 2 + mm][n] = __builtin_amdgcn_mfma_f32_16x16x32_bf16(
                af[mm][ks], bfv[n][ks], acc[q * 2 + mm][n], 0, 0, 0);
      __builtin_amdgcn_s_setprio(0);
      __builtin_amdgcn_s_barrier();
    }
    asm volatile("s_waitcnt vmcnt(0)" ::: "memory");
    __builtin_amdgcn_s_barrier();
    cur ^= 1;
  }

#pragma unroll
  for (int m = 0; m < 8; ++m) {
    const int gr0 = m0 + wr * 128 + m * 16 + l4 * 4;
    const int bb = gr0 >> 11;
    const int nn0 = gr0 & 2047;
#pragma unroll
    for (int n = 0; n < 4; ++n) {
      const int gc = n0 + wc * 64 + n * 16 + l15;
      if (gc < 3072) {
        const int t = gc >> 10, hd = gc & 1023;
        const int h = hd >> 6, d = hd & 63;
        const int base = ((bb * 16 + h) * 2048 + nn0) * 64 + d;
        if (t == 0) {
#pragma unroll
          for (int r = 0; r < 4; ++r)
            p.q[base + r * 64] = __float2bfloat16(acc[m][n][r] * QSCALE);
        } else if (t == 1) {
#pragma unroll
          for (int r = 0; r < 4; ++r)
            p.k[base + r * 64] =
                __float2bfloat16(acc[m][n][r] + __bfloat162float(p.sT[base + r * 64]));
        } else {
          union { bf16 h4[4]; s16x4 s; } u;
#pragma unroll
          for (int r = 0; r < 4; ++r) u.h4[r] = __float2bfloat16(acc[m][n][r]);
          *reinterpret_cast<s16x4*>(&p.vt[((bb * 16 + h) * 64 + d) * 2048 + nn0]) = u.s;
        }
      } else {
        const int gcc = gc - 3072;
#pragma unroll
        for (int r = 0; r < 4; ++r)
          p.gate[(gr0 + r) * 1024 + gcc] = __float2bfloat16(acc[m][n][r]);
      }
    }
  }
}

// ---------------- 128x64-tile 2-phase GEMM, BK=64, 4 waves (s-GEMM & proj) ----------------
// Same sync skeleton as gemm256_k: front-loaded staging, per-phase barriers,
// single vmcnt(0)+barrier per K-tile. 512 blocks = 2/CU. XOR-swizzled LDS.
template <int EPI>
__global__ __launch_bounds__(256) void gemm128_k(GemmP p) {
  constexpr int K = 1024;
  constexpr int NT = 16;  // K/64
  __shared__ bf16 AB[2][128 * 64 + 64 * 64];  // A then B
  const int tid = threadIdx.x;
  const int wid = tid >> 6, lane = tid & 63;
  const int l15 = lane & 15, l4 = lane >> 4;
  const int wr = wid >> 1, wc = wid & 1;  // 2x2 waves, each 64x32 output

  const int bid0 = blockIdx.y * 16 + blockIdx.x;
  const int bid = (bid0 & 7) * 64 + (bid0 >> 3);  // bijective (512%8==0)
  const int m0 = (bid >> 4) * 128, n0 = (bid & 15) * 64;

  const bf16* Arow = p.A + (size_t)m0 * K;
  const bf16* Brow = p.B0 + (size_t)n0 * K;

  f32x4 acc[4][2];
#pragma unroll
  for (int m = 0; m < 4; ++m)
#pragma unroll
    for (int n = 0; n < 2; ++n) acc[m][n] = zf4();

  const int srow = tid >> 3, sc = tid & 7;  // 32 rows/sweep
  auto stageA = [&](int b, int kt) {
#pragma unroll
    for (int s = 0; s < 4; ++s) {
      const int r = s * 32 + srow;
      const int c2 = sc ^ (r & 7);
      gl_lds16(Arow + (size_t)r * K + kt * 64 + c2 * 8, &AB[b][r * 64 + sc * 8]);
    }
  };
  auto stageB = [&](int b, int kt) {
#pragma unroll
    for (int s = 0; s < 2; ++s) {
      const int r = s * 32 + srow;
      const int c2 = sc ^ (r & 7);
      gl_lds16(Brow + (size_t)r * K + kt * 64 + c2 * 8, &AB[b][8192 + r * 64 + sc * 8]);
    }
  };

  stageA(0, 0);
  stageB(0, 0);
  __syncthreads();
  int cur = 0;

  for (int kt = 0; kt < NT; ++kt) {
    bf16x8 bfv[2][2];
#pragma unroll
    for (int q = 0; q < 2; ++q) {
      bf16x8 af[2][2];
#pragma unroll
      for (int mm = 0; mm < 2; ++mm) {
        const int row = wr * 64 + (q * 2 + mm) * 16 + l15;
#pragma unroll
        for (int ks = 0; ks < 2; ++ks)
          af[mm][ks] = *reinterpret_cast<const bf16x8*>(
              &AB[cur][row * 64 + ((ks * 4 + l4) ^ (row & 7)) * 8]);
      }
      if (q == 0) {
#pragma unroll
        for (int n = 0; n < 2; ++n) {
          const int row = wc * 32 + n * 16 + l15;
#pragma unroll
          for (int ks = 0; ks < 2; ++ks)
            bfv[n][ks] = *reinterpret_cast<const bf16x8*>(
                &AB[cur][8192 + row * 64 + ((ks * 4 + l4) ^ (row & 7)) * 8]);
        }
      }
      if (q == 0 && kt + 1 < NT) stageA(cur ^ 1, kt + 1);
      if (q == 1 && kt + 1 < NT) stageB(cur ^ 1, kt + 1);

      __builtin_amdgcn_s_barrier();
      __builtin_amdgcn_s_setprio(1);
#pragma unroll
      for (int mm = 0; mm < 2; ++mm)
#pragma unroll
        for (int n = 0; n < 2; ++n)
#pragma unroll
          for (int ks = 0; ks < 2; ++ks)
            acc[q * 2 + mm][n] = __builtin_amdgcn_mfma_f32_16x16x32_bf16(
                af[mm][ks], bfv[n][ks], acc[q * 2 + mm][n], 0, 0, 0);
      __builtin_amdgcn_s_setprio(0);
      __builtin_amdgcn_s_barrier();
    }
    asm volatile("s_waitcnt vmcnt(0)" ::: "memory");
    __builtin_amdgcn_s_barrier();
    cur ^= 1;
  }

#pragma unroll
  for (int m = 0; m < 4; ++m) {
    const int gr0 = m0 + wr * 64 + m * 16 + l4 * 4;
    const int bb = gr0 >> 11;
    const int nn0 = gr0 & 2047;
#pragma unroll
    for (int n = 0; n < 2; ++n) {
      const int gc = n0 + wc * 32 + n * 16 + l15;
      if (EPI == 0) {
        const int h = gc >> 6, d = gc & 63;
        bf16* dst = p.obf + ((bb * 16 + h) * 2048 + nn0) * 64 + d;
#pragma unroll
        for (int r = 0; r < 4; ++r) dst[r * 64] = __float2bfloat16(acc[m][n][r]);
      } else {
        const float bias = p.bias[gc];
#pragma unroll
        for (int r = 0; r < 4; ++r) p.out[(gr0 + r) * 1024 + gc] = acc[m][n][r] + bias;
      }
    }
  }
}

// ---------------- flash attention: 32 q-rows/wave, K/V frags reused x2 (unchanged) ----------------
__global__ __launch_bounds__(256) void flash_k(const bf16* __restrict__ qT,
                                               const bf16* __restrict__ kTb,
                                               const bf16* __restrict__ vTt,
                                               const bf16* __restrict__ gateb,
                                               bf16* __restrict__ attng) {
  __shared__ bf16 Ks[2][64 * 64];
  __shared__ bf16 Vs[2][64 * 64];
  const int tid = threadIdx.x;
  const int wid = tid >> 6, lane = tid & 63;
  const int l15 = lane & 15, l4 = lane >> 4;
  const int hbit = lane >> 5;
  const int qt = blockIdx.x, bh = blockIdx.y;
  const int qr0 = qt * 128 + wid * 32;
  const bf16* qbase = qT + (bh * 2048 + qr0) * 64;
  bf16x8 qf[2][2];
#pragma unroll
  for (int g = 0; g < 2; ++g)
#pragma unroll
    for (int kk = 0; kk < 2; ++kk)
      qf[g][kk] = *reinterpret_cast<const bf16x8*>(
          &qbase[(g * 16 + l15) * 64 + kk * 32 + 8 * l4]);
  const bf16* kbase = kTb + bh * 2048 * 64;
  const bf16* vbase = vTt + bh * 64 * 2048;
  const int srcQ0 = (((lane & 16) << 1) | (lane & 15)) << 2;
  const int srcQ1 = srcQ0 | 64;

  f32x4 o[2][4];
#pragma unroll
  for (int g = 0; g < 2; ++g)
#pragma unroll
    for (int i = 0; i < 4; ++i) o[g][i] = zf4();
  float mrun[2] = {-1e30f, -1e30f}, lrun[2] = {0.f, 0.f};
  const int srow = tid >> 3, sc = tid & 7;

  auto stage = [&](int b, int kt) {
#pragma unroll
    for (int it = 0; it < 2; ++it) {
      const int row = it * 32 + srow;
      const int c2 = sc ^ (row & 7);
      gl_lds16(kbase + (kt * 64 + row) * 64 + c2 * 8, &Ks[b][it * 2048 + wid * 512]);
      gl_lds16(vbase + row * 2048 + kt * 64 + c2 * 8, &Vs[b][it * 2048 + wid * 512]);
    }
  };

  stage(0, 0);
  __syncthreads();
  int cur = 0;

  for (int kt = 0; kt < 32; ++kt) {
    if (kt < 31) stage(cur ^ 1, kt + 1);

    f32x4 sa[2][4];
#pragma unroll
    for (int g = 0; g < 2; ++g)
#pragma unroll
      for (int n = 0; n < 4; ++n) sa[g][n] = zf4();
    __builtin_amdgcn_s_setprio(1);
#pragma unroll
    for (int kk = 0; kk < 2; ++kk) {
#pragma unroll
      for (int n = 0; n < 4; ++n) {
        const int key = n * 16 + l15;
        const bf16x8 kv = *reinterpret_cast<const bf16x8*>(
            &Ks[cur][key * 64 + ((kk * 4 + l4) ^ (key & 7)) * 8]);
#pragma unroll
        for (int g = 0; g < 2; ++g)
          sa[g][n] = __builtin_amdgcn_mfma_f32_16x16x32_bf16(kv, qf[g][kk], sa[g][n], 0, 0, 0);
      }
    }
    __builtin_amdgcn_s_setprio(0);

    float mt[2];
#pragma unroll
    for (int g = 0; g < 2; ++g) {
      float m = sa[g][0][0];
#pragma unroll
      for (int n = 0; n < 4; ++n)
#pragma unroll
        for (int r = 0; r < 4; ++r) m = fmaxf(m, sa[g][n][r]);
      m = fmaxf(m, __shfl_xor(m, 16, 64));
      mt[g] = fmaxf(m, __shfl_xor(m, 32, 64));
    }

    const int okg = (mt[0] <= mrun[0] + RESCALE_THR) & (mt[1] <= mrun[1] + RESCALE_THR);
    const bool upd = !__all(okg);
    float fac[2] = {1.f, 1.f};
    if (upd) {
#pragma unroll
      for (int g = 0; g < 2; ++g) {
        const float mn = fmaxf(mrun[g], mt[g]);
        fac[g] = fexp2(mrun[g] - mn);
        mrun[g] = mn;
      }
    }

    int Cp[2][4][2];
#pragma unroll
    for (int g = 0; g < 2; ++g) {
      float psum = 0.f;
      float p[4][4];
#pragma unroll
      for (int n = 0; n < 4; ++n)
#pragma unroll
        for (int r = 0; r < 4; ++r) {
          p[n][r] = fexp2(sa[g][n][r] - mrun[g]);
          psum += p[n][r];
        }
      psum += __shfl_xor(psum, 16, 64);
      psum += __shfl_xor(psum, 32, 64);
      if (upd) {
        lrun[g] = lrun[g] * fac[g] + psum;
#pragma unroll
        for (int nd = 0; nd < 4; ++nd)
#pragma unroll
          for (int r = 0; r < 4; ++r) o[g][nd][r] *= fac[g];
      } else {
        lrun[g] += psum;
      }
#pragma unroll
      for (int n = 0; n < 4; ++n) {
        Cp[g][n][0] = (int)cvt_pk_bf16(p[n][0], p[n][1]);
        Cp[g][n][1] = (int)cvt_pk_bf16(p[n][2], p[n][3]);
      }
    }

    __builtin_amdgcn_s_setprio(1);
#pragma unroll
    for (int kk = 0; kk < 2; ++kk) {
      bf16x8 pw[2];
#pragma unroll
      for (int g = 0; g < 2; ++g) {
        const int x0 = __builtin_amdgcn_ds_bpermute(srcQ0, Cp[g][2 * kk][0]);
        const int x1 = __builtin_amdgcn_ds_bpermute(srcQ0, Cp[g][2 * kk + 1][0]);
        const int y0 = __builtin_amdgcn_ds_bpermute(srcQ0, Cp[g][2 * kk][1]);
        const int y1 = __builtin_amdgcn_ds_bpermute(srcQ0, Cp[g][2 * kk + 1][1]);
        const int z0 = __builtin_amdgcn_ds_bpermute(srcQ1, Cp[g][2 * kk][0]);
        const int z1 = __builtin_amdgcn_ds_bpermute(srcQ1, Cp[g][2 * kk + 1][0]);
        const int t0 = __builtin_amdgcn_ds_bpermute(srcQ1, Cp[g][2 * kk][1]);
        const int t1 = __builtin_amdgcn_ds_bpermute(srcQ1, Cp[g][2 * kk + 1][1]);
        union { int u[4]; bf16x8 v; } u;
        u.u[0] = hbit ? x1 : x0;
        u.u[1] = hbit ? y1 : y0;
        u.u[2] = hbit ? z1 : z0;
        u.u[3] = hbit ? t1 : t0;
        pw[g] = u.v;
      }
#pragma unroll
      for (int nd = 0; nd < 4; ++nd) {
        const int d = nd * 16 + l15;
        const bf16x8 vv = *reinterpret_cast<const bf16x8*>(
            &Vs[cur][d * 64 + ((kk * 4 + l4) ^ (d & 7)) * 8]);
#pragma unroll
        for (int g = 0; g < 2; ++g)
          o[g][nd] = __builtin_amdgcn_mfma_f32_16x16x32_bf16(vv, pw[g], o[g][nd], 0, 0, 0);
      }
    }
    __builtin_amdgcn_s_setprio(0);

    __syncthreads();
    cur ^= 1;
  }

  const int bb = bh >> 4, h = bh & 15;
#pragma unroll
  for (int g = 0; g < 2; ++g) {
    const int grow = bb * 2048 + qr0 + g * 16 + l15;
    const float inv = 1.0f / lrun[g];
#pragma unroll
    for (int nd = 0; nd < 4; ++nd) {
      const int gi = grow * 1024 + h * 64 + nd * 16 + l4 * 4;
      union { s16x4 s; bf16 h4[4]; } gu, ou;
      gu.s = *reinterpret_cast<const s16x4*>(&gateb[gi]);
#pragma unroll
      for (int r = 0; r < 4; ++r)
        ou.h4[r] = __float2bfloat16(o[g][nd][r] * inv * __bfloat162float(gu.h4[r]));
      *reinterpret_cast<s16x4*>(&attng[gi]) = ou.s;
    }
  }
}

// ---------------- launcher ----------------
extern "C" void kernel_launch(void* const* d_in, const int* in_sizes, int n_in,
                              void* d_out, int out_size, void* d_ws, size_t ws_size,
                              hipStream_t stream) {
  const float* x = (const float*)d_in[0];
  const float* e = (const float*)d_in[1];
  const float* Wqkv = (const float*)d_in[2];
  const float* Ws = (const float*)d_in[3];
  const float* Wgate = (const float*)d_in[4];
  const float* Wproj = (const float*)d_in[5];
  const float* bproj = (const float*)d_in[6];
  float* out = (float*)d_out;

  char* w = (char*)d_ws;
  auto carve = [&](size_t bytes) -> void* {
    void* p = (void*)w;
    w += (bytes + 255) & ~size_t(255);
    return p;
  };
  // time-disjoint aliases: qT overlays ebf (dead after gemm128<0>);
  // attng overlays sT (dead after gemm256).
  bf16* xbf    = (bf16*)carve(4096UL * 1024 * 2);
  bf16* ebf    = (bf16*)carve(4096UL * 1024 * 2);
  bf16* Wqkvt  = (bf16*)carve(3072UL * 1024 * 2);
  bf16* Wst    = (bf16*)carve(1024UL * 1024 * 2);
  bf16* Wgatet = (bf16*)carve(1024UL * 1024 * 2);
  bf16* Wprojt = (bf16*)carve(1024UL * 1024 * 2);
  bf16* kTb    = (bf16*)carve(32UL * 2048 * 64 * 2);
  bf16* vTt    = (bf16*)carve(32UL * 64 * 2048 * 2);
  bf16* sT     = (bf16*)carve(32UL * 2048 * 64 * 2);
  bf16* gateb  = (bf16*)carve(4096UL * 1024 * 2);
  bf16* qT     = ebf;
  bf16* attng  = sT;

  PrepP tp{};
  tp.s[0] = Wqkv; tp.s[1] = Ws; tp.s[2] = Wgate; tp.s[3] = Wproj;
  tp.d[0] = Wqkvt; tp.d[1] = Wst; tp.d[2] = Wgatet; tp.d[3] = Wprojt;
  tp.x = x; tp.e = e; tp.xb = xbf; tp.eb = ebf;
  prep_k<<<dim3(32, 32, 7), 256, 0, stream>>>(tp);

  GemmP ps{};
  ps.A = ebf; ps.B0 = Wst; ps.obf = sT;
  gemm128_k<0><<<dim3(16, 32), 256, 0, stream>>>(ps);

  GemmP pq{};
  pq.A = xbf; pq.B0 = Wqkvt; pq.B1 = Wgatet; pq.sT = sT;
  pq.q = qT; pq.k = kTb; pq.vt = vTt; pq.gate = gateb;
  gemm256_k<<<dim3(16, 16), 512, 0, stream>>>(pq);

  flash_k<<<dim3(16, 32), 256, 0, stream>>>(qT, kTb, vTt, gateb, attng);

  GemmP pp{};
  pp.A = attng; pp.B0 = Wprojt; pp.out = out; pp.bias = bproj;
  gemm128_k<1><<<dim3(16, 32), 256, 0, stream>>>(pp);
}